// Round 9
// baseline (212.402 us; speedup 1.0000x reference)
//
#include <hip/hip_runtime.h>
#include <math.h>

typedef unsigned short ushort_t;
typedef short short4x __attribute__((ext_vector_type(4)));
typedef short short8 __attribute__((ext_vector_type(8)));
typedef float f32x4 __attribute__((ext_vector_type(4)));
typedef float f32x16 __attribute__((ext_vector_type(16)));

#define MFMA32(A,B,C) __builtin_amdgcn_mfma_f32_32x32x16_bf16(A,B,C,0,0,0)
#define MFMA16(A,B,C) __builtin_amdgcn_mfma_f32_16x16x32_bf16(A,B,C,0,0,0)

__device__ __forceinline__ ushort_t f2bf(float f) {
    union { float f; unsigned u; } c; c.f = f;
    unsigned u = c.u;
    unsigned r = (u + 0x7FFFu + ((u >> 16) & 1u)) >> 16;
    return (ushort_t)r;
}

__device__ __forceinline__ unsigned pk2bf(float lo, float hi) {
    unsigned r;
    asm("v_cvt_pk_bf16_f32 %0, %1, %2" : "=v"(r) : "v"(lo), "v"(hi));
    return r;
}

// ---------- weight repack + output-scalar zeroing ----------
// conv2/3/4 (16x16x32 path): frag value(lane,j) = W[oc = ocg*16+(lane&15)][ic = (lane>>4)*8+j][tau]
// conv1 (32x32x16 path): k = pixel*4 + channel as before.
__global__ __launch_bounds__(256) void k_wcvt(
    const float* __restrict__ c1w, const float* __restrict__ c2w,
    const float* __restrict__ c3w, const float* __restrict__ c4w,
    ushort_t* __restrict__ c1f, ushort_t* __restrict__ w2f,
    ushort_t* __restrict__ w3f, ushort_t* __restrict__ w4f,
    float* __restrict__ feat, float* __restrict__ tail)
{
    if (blockIdx.x == 33) {   // zero feat + tail
        for (int i = threadIdx.x; i < 8192; i += 256) feat[i] = 0.f;
        if (threadIdx.x < 33) tail[threadIdx.x] = 0.f;
        return;
    }
    int r = blockIdx.x * 256 + threadIdx.x;
    int f = r >> 6, lane = r & 63;
    int col = lane & 15, kg = lane >> 4;
    if (f < 18) {                          // conv2: f = tau*2 + ocg
        int tau = f >> 1, ocg = f & 1;
        int oc = ocg * 16 + col;
        #pragma unroll
        for (int j = 0; j < 8; ++j) {
            int ic = kg * 8 + j;
            w2f[r * 8 + j] = f2bf(c2w[(oc * 32 + ic) * 9 + tau]);
        }
    } else if (f < 54) {                   // conv3: rr = tau*4 + ocg
        int rr = f - 18;
        int tau = rr >> 2, ocg = rr & 3;
        int oc = ocg * 16 + col;
        #pragma unroll
        for (int j = 0; j < 8; ++j) {
            int ic = kg * 8 + j;
            w3f[(r - 18 * 64) * 8 + j] = f2bf(c3w[(oc * 32 + ic) * 9 + tau]);
        }
    } else if (f < 126) {                  // conv4: rr = (tau*2+ks)*4 + ocg
        int rr = f - 54;
        int q = rr >> 2, ocg = rr & 3, tau = q >> 1, ks = q & 1;
        int oc = ocg * 16 + col;
        #pragma unroll
        for (int j = 0; j < 8; ++j) {
            int ic = ks * 32 + kg * 8 + j;
            w4f[(r - 54 * 64) * 8 + j] = f2bf(c4w[(oc * 64 + ic) * 9 + tau]);
        }
    } else if (f < 129) {                  // conv1: 3 frags, k = p*4 + c (K=48)
        int rr = r - 126 * 64;             // 0..191
        int f1 = rr >> 6;                  // 0..2
        int m = lane & 31, g = (lane >> 5) & 1;
        #pragma unroll
        for (int j = 0; j < 8; ++j) {
            int k = f1 * 16 + g * 8 + j;
            int p = k >> 2, c = k & 3;
            ushort_t v = 0;
            if (p < 9 && c < 3)
                v = f2bf(c1w[(m * 3 + c) * 9 + p]);
            c1f[rr * 8 + j] = v;
        }
    }
}

// ---------- K_A: conv1 (MFMA32) + conv2 (MFMA16, in-lane pool) -> a2 bf16 NHWC [128][64][64][32]
// grid (8,8,128): tile = 16x16 conv2 outputs = 8x8 pool quads. 8 waves.
__global__ __launch_bounds__(512, 4) void k_c12(
    const float* __restrict__ x,
    const ushort_t* __restrict__ c1f, const float* __restrict__ c1b,
    const ushort_t* __restrict__ w2f, const float* __restrict__ c2b,
    ushort_t* __restrict__ a2)
{
    __shared__ __align__(16) ushort_t xs[1600];        // x tile [20][20][4] (c fastest, pad)
    __shared__ __align__(16) ushort_t a1s[324 * 40];   // 18x18 cells, 32 ic + 8 pad
    __shared__ float c2bs[32], c1bs[32];
    const int t = threadIdx.x;
    const int bx = blockIdx.x, by = blockIdx.y, b = blockIdx.z;
    const int ox0 = bx * 16, oy0 = by * 16;

    if (t < 32) { c2bs[t] = c2b[t]; c1bs[t] = c1b[t]; }
    for (int i = t; i < 400; i += 512) {
        int yy = i / 20, xx = i % 20;
        int gy = oy0 - 2 + yy, gx = ox0 - 2 + xx;
        float v0 = 0.f, v1 = 0.f, v2 = 0.f;
        if (gy >= 0 && gy < 128 && gx >= 0 && gx < 128) {
            const float* px = x + ((size_t)(b * 3) * 128 + gy) * 128 + gx;
            v0 = px[0]; v1 = px[16384]; v2 = px[32768];
        }
        uint2 pk;
        pk.x = pk2bf(v0, v1);
        pk.y = pk2bf(v2, 0.f);
        *(uint2*)&xs[i * 4] = pk;
    }

    const int wave = t >> 6, lane = t & 63;
    const int n = lane & 31, g = lane >> 5;

    short8 a1f0 = *(const short8*)(c1f + lane * 8);
    short8 a1f1 = *(const short8*)(c1f + (64 + lane) * 8);
    short8 a1f2 = *(const short8*)(c1f + (128 + lane) * 8);
    __syncthreads();

    // per-lane conv1 bias (row mapping: oc = 8*qd + 4*g + jj)
    float cb1[16];
    #pragma unroll
    for (int qd = 0; qd < 4; ++qd)
        #pragma unroll
        for (int jj = 0; jj < 4; ++jj)
            cb1[qd * 4 + jj] = c1bs[qd * 8 + 4 * g + jj];

    // ---- conv1 via MFMA32 over 11 groups of 32 halo cells (324) ----
    for (int grp = wave; grp < 11; grp += 8) {
        int q = grp * 32 + n;
        bool qv = q < 324;
        int qc = qv ? q : 0;
        int cy = qc / 18, cx = qc % 18;
        int gy = oy0 - 1 + cy, gx = ox0 - 1 + cx;
        bool inimg = qv && gy >= 0 && gy < 128 && gx >= 0 && gx < 128;
        int base = (cy * 20 + cx) * 4;

        short4x q0 = *(const short4x*)&xs[base + (g ? 8 : 0)];
        short4x q1 = *(const short4x*)&xs[base + (g ? 80 : 4)];
        short4x q2 = *(const short4x*)&xs[base + (g ? 160 : 84)];
        short4x q3 = *(const short4x*)&xs[base + (g ? 164 : 88)];
        short4x q4 = *(const short4x*)&xs[base + 168];

        short8 b0 = __builtin_shufflevector(q0, q1, 0, 1, 2, 3, 4, 5, 6, 7);
        short8 b1 = __builtin_shufflevector(q2, q3, 0, 1, 2, 3, 4, 5, 6, 7);
        short8 b2 = __builtin_shufflevector(q4, q4, 0, 1, 2, 3, 0, 1, 2, 3);

        f32x16 acc;
        #pragma unroll
        for (int i = 0; i < 16; ++i) acc[i] = 0.f;
        acc = MFMA32(a1f0, b0, acc);
        acc = MFMA32(a1f1, b1, acc);
        acc = MFMA32(a1f2, b2, acc);

        if (qv) {
            ushort_t* dst = &a1s[q * 40 + 4 * g];
            #pragma unroll
            for (int qd = 0; qd < 4; ++qd) {
                float v0 = fmaxf(acc[qd * 4 + 0] + cb1[qd * 4 + 0], 0.f);
                float v1 = fmaxf(acc[qd * 4 + 1] + cb1[qd * 4 + 1], 0.f);
                float v2 = fmaxf(acc[qd * 4 + 2] + cb1[qd * 4 + 2], 0.f);
                float v3 = fmaxf(acc[qd * 4 + 3] + cb1[qd * 4 + 3], 0.f);
                uint2 pk;
                pk.x = inimg ? pk2bf(v0, v1) : 0u;
                pk.y = inimg ? pk2bf(v2, v3) : 0u;
                *(uint2*)&dst[8 * qd] = pk;
            }
        }
    }
    __syncthreads();

    // ---- conv2 via MFMA16: A = positions (rows), B = weights (cols=oc) ----
    const int col = lane & 15, kg = lane >> 4;
    const float bias0 = c2bs[col], bias1 = c2bs[16 + col];
    #pragma unroll
    for (int i = 0; i < 2; ++i) {
        const int pg = wave * 2 + i;                 // 16 pos-groups of 16 positions (4 quads)
        const int qiA = pg * 4 + (col >> 2), subA = col & 3;
        const int y2 = (qiA >> 3) * 2 + (subA >> 1);
        const int x2 = (qiA & 7) * 2 + (subA & 1);
        const ushort_t* abase = &a1s[(y2 * 18 + x2) * 40 + kg * 8];
        f32x4 acc0 = {0.f, 0.f, 0.f, 0.f}, acc1 = {0.f, 0.f, 0.f, 0.f};
        #pragma unroll
        for (int tau = 0; tau < 9; ++tau) {
            short8 a = *(const short8*)(abase + ((tau / 3) * 18 + (tau % 3)) * 40);
            short8 w0 = *(const short8*)(w2f + ((tau * 2 + 0) * 64 + lane) * 8);
            short8 w1 = *(const short8*)(w2f + ((tau * 2 + 1) * 64 + lane) * 8);
            acc0 = MFMA16(a, w0, acc0);
            acc1 = MFMA16(a, w1, acc1);
        }
        const int qo = pg * 4 + kg;                  // this lane's output quad
        const int poy = by * 8 + (qo >> 3), pox = bx * 8 + (qo & 7);
        float s0 = fmaxf(acc0[0] + bias0, 0.f) + fmaxf(acc0[1] + bias0, 0.f)
                 + fmaxf(acc0[2] + bias0, 0.f) + fmaxf(acc0[3] + bias0, 0.f);
        float s1 = fmaxf(acc1[0] + bias1, 0.f) + fmaxf(acc1[1] + bias1, 0.f)
                 + fmaxf(acc1[2] + bias1, 0.f) + fmaxf(acc1[3] + bias1, 0.f);
        ushort_t* dst = &a2[(((size_t)b * 64 + poy) * 64 + pox) * 32];
        dst[col] = f2bf(s0 * 0.25f);
        dst[16 + col] = f2bf(s1 * 0.25f);
    }
}

// ---------- K_B: conv3 (MFMA16, in-lane pool) -> a3 bf16 NHWC [128][32][32][64]
// grid (4,4,128), 512 thr: tile 16x16 conv3 outputs.
__global__ __launch_bounds__(512, 4) void k_c3(
    const ushort_t* __restrict__ a2, const ushort_t* __restrict__ w3f,
    const float* __restrict__ c3b, ushort_t* __restrict__ a3)
{
    __shared__ __align__(16) ushort_t s[324 * 40];
    __shared__ float bs[64];
    const int t = threadIdx.x;
    const int bx = blockIdx.x, by = blockIdx.y, b = blockIdx.z;
    const int x0 = bx * 16, y0 = by * 16;
    if (t < 64) bs[t] = c3b[t];
    for (int idx = t; idx < 1296; idx += 512) {
        int cell = idx >> 2, part = idx & 3;
        int cy = cell / 18, cx = cell % 18;
        int gy = y0 - 1 + cy, gx = x0 - 1 + cx;
        uint4 v = make_uint4(0, 0, 0, 0);
        if (gy >= 0 && gy < 64 && gx >= 0 && gx < 64)
            v = *(const uint4*)(a2 + (((size_t)b * 64 + gy) * 64 + gx) * 32 + part * 8);
        *(uint4*)(&s[cell * 40 + part * 8]) = v;
    }
    __syncthreads();

    const int wave = t >> 6, lane = t & 63;
    const int col = lane & 15, kg = lane >> 4;
    float bias[4];
    #pragma unroll
    for (int ocg = 0; ocg < 4; ++ocg) bias[ocg] = bs[ocg * 16 + col];

    #pragma unroll
    for (int i = 0; i < 2; ++i) {
        const int pg = wave * 2 + i;
        const int qiA = pg * 4 + (col >> 2), subA = col & 3;
        const int y3 = (qiA >> 3) * 2 + (subA >> 1);
        const int x3 = (qiA & 7) * 2 + (subA & 1);
        const ushort_t* abase = &s[(y3 * 18 + x3) * 40 + kg * 8];
        f32x4 acc[4];
        #pragma unroll
        for (int ocg = 0; ocg < 4; ++ocg) acc[ocg] = f32x4{0.f, 0.f, 0.f, 0.f};
        #pragma unroll
        for (int tau = 0; tau < 9; ++tau) {
            short8 a = *(const short8*)(abase + ((tau / 3) * 18 + (tau % 3)) * 40);
            #pragma unroll
            for (int ocg = 0; ocg < 4; ++ocg) {
                short8 wv = *(const short8*)(w3f + ((tau * 4 + ocg) * 64 + lane) * 8);
                acc[ocg] = MFMA16(a, wv, acc[ocg]);
            }
        }
        const int qo = pg * 4 + kg;
        const int poy = by * 8 + (qo >> 3), pox = bx * 8 + (qo & 7);
        ushort_t* dst = &a3[(((size_t)b * 32 + poy) * 32 + pox) * 64];
        #pragma unroll
        for (int ocg = 0; ocg < 4; ++ocg) {
            float sv = fmaxf(acc[ocg][0] + bias[ocg], 0.f) + fmaxf(acc[ocg][1] + bias[ocg], 0.f)
                     + fmaxf(acc[ocg][2] + bias[ocg], 0.f) + fmaxf(acc[ocg][3] + bias[ocg], 0.f);
            dst[ocg * 16 + col] = f2bf(sv * 0.25f);
        }
    }
}

// ---------- K_C: conv4 (MFMA16) + relu + global mean -> feat f32 [128][64]
// grid (2,2,128), 512 thr: tile 16x16 conv4 outputs.
__global__ __launch_bounds__(512, 4) void k_c4(
    const ushort_t* __restrict__ a3, const ushort_t* __restrict__ w4f,
    const float* __restrict__ c4b, float* __restrict__ feat)
{
    __shared__ __align__(16) ushort_t s[324 * 72];
    __shared__ float bs[64];
    __shared__ float fp[64];
    const int t = threadIdx.x;
    const int bx = blockIdx.x, by = blockIdx.y, b = blockIdx.z;
    const int x0 = bx * 16, y0 = by * 16;
    if (t < 64) { bs[t] = c4b[t]; fp[t] = 0.f; }
    for (int idx = t; idx < 2592; idx += 512) {
        int cell = idx >> 3, part = idx & 7;
        int cy = cell / 18, cx = cell % 18;
        int gy = y0 - 1 + cy, gx = x0 - 1 + cx;
        uint4 v = make_uint4(0, 0, 0, 0);
        if (gy >= 0 && gy < 32 && gx >= 0 && gx < 32)
            v = *(const uint4*)(a3 + (((size_t)b * 32 + gy) * 32 + gx) * 64 + part * 8);
        *(uint4*)(&s[cell * 72 + part * 8]) = v;
    }
    __syncthreads();

    const int wave = t >> 6, lane = t & 63;
    const int col = lane & 15, kg = lane >> 4;
    float bias[4], fpart[4] = {0.f, 0.f, 0.f, 0.f};
    #pragma unroll
    for (int ocg = 0; ocg < 4; ++ocg) bias[ocg] = bs[ocg * 16 + col];

    #pragma unroll
    for (int i = 0; i < 2; ++i) {
        const int pg = wave * 2 + i;
        const int qiA = pg * 4 + (col >> 2), subA = col & 3;
        const int y4 = (qiA >> 3) * 2 + (subA >> 1);
        const int x4 = (qiA & 7) * 2 + (subA & 1);
        const ushort_t* abase = &s[(y4 * 18 + x4) * 72 + kg * 8];
        f32x4 acc[4];
        #pragma unroll
        for (int ocg = 0; ocg < 4; ++ocg) acc[ocg] = f32x4{0.f, 0.f, 0.f, 0.f};
        #pragma unroll
        for (int tau = 0; tau < 9; ++tau) {
            #pragma unroll
            for (int ks = 0; ks < 2; ++ks) {
                short8 a = *(const short8*)(abase + ((tau / 3) * 18 + (tau % 3)) * 72 + ks * 32);
                #pragma unroll
                for (int ocg = 0; ocg < 4; ++ocg) {
                    short8 wv = *(const short8*)(w4f + (((tau * 2 + ks) * 4 + ocg) * 64 + lane) * 8);
                    acc[ocg] = MFMA16(a, wv, acc[ocg]);
                }
            }
        }
        #pragma unroll
        for (int ocg = 0; ocg < 4; ++ocg) {
            fpart[ocg] += fmaxf(acc[ocg][0] + bias[ocg], 0.f) + fmaxf(acc[ocg][1] + bias[ocg], 0.f)
                        + fmaxf(acc[ocg][2] + bias[ocg], 0.f) + fmaxf(acc[ocg][3] + bias[ocg], 0.f);
        }
    }
    // reduce across the 4 kg groups (same col), then accumulate via LDS
    #pragma unroll
    for (int ocg = 0; ocg < 4; ++ocg) {
        float v = fpart[ocg];
        v += __shfl_xor(v, 16);
        v += __shfl_xor(v, 32);
        if (lane < 16) atomicAdd(&fp[ocg * 16 + col], v);
    }
    __syncthreads();
    if (t < 64) atomicAdd(&feat[b * 64 + t], fp[t] * (1.0f / 1024.0f));
}

// ---------- router ----------
__global__ __launch_bounds__(256) void k_router(
    const float* __restrict__ meanacc,
    const float* __restrict__ pw, const float* __restrict__ pb,
    const float* __restrict__ rw, const float* __restrict__ rb,
    ushort_t* __restrict__ zb, int* __restrict__ top1, float* __restrict__ tail)
{
    __shared__ float m[64];
    __shared__ float zs[512];
    __shared__ float part[256];
    __shared__ float gate[16];
    const int b = blockIdx.x, t = threadIdx.x;
    if (t < 64) m[t] = meanacc[b * 64 + t];
    __syncthreads();

    #pragma unroll
    for (int j = 0; j < 2; ++j) {
        int d = t + j * 256;
        float s = pb[d];
        for (int c = 0; c < 64; ++c) s += m[c] * pw[c * 512 + d];
        zs[d] = s;
        zb[b * 512 + d] = f2bf(s);
    }
    __syncthreads();
    {
        int e = t & 15, gg = t >> 4;
        float s = 0.f;
        for (int j = 0; j < 32; ++j) {
            int d = gg * 32 + j;
            s += zs[d] * rw[d * 16 + e];
        }
        part[t] = s;
    }
    __syncthreads();
    if (t < 16) {
        float s = rb[t];
        for (int gg = 0; gg < 16; ++gg) s += part[gg * 16 + t];
        gate[t] = s;
    }
    __syncthreads();
    if (t == 0) {
        float mx = gate[0];
        int am = 0;
        for (int e = 1; e < 16; ++e)
            if (gate[e] > mx) { mx = gate[e]; am = e; }
        float pr[16];
        float sum = 0.f;
        for (int e = 0; e < 16; ++e) { pr[e] = expf(gate[e] - mx); sum += pr[e]; }
        float inv = 1.f / sum;
        top1[b] = am;
        atomicAdd(&tail[1 + am], 1.0f / 128.0f);
        for (int e = 0; e < 16; ++e)
            atomicAdd(&tail[17 + e], pr[e] * inv * (1.0f / 128.0f));
    }
}

// ---------- token sort + tile list + aux ----------
__global__ void k_sort(const int* __restrict__ top1, int* __restrict__ meta,
                       int* __restrict__ perm, float* __restrict__ tail)
{
    __shared__ int c[16], o[16], pos[128];
    const int t = threadIdx.x;
    if (t < 16) c[t] = 0;
    __syncthreads();
    int e = 0;
    if (t < 128) { e = top1[t]; pos[t] = atomicAdd(&c[e], 1); }
    __syncthreads();
    if (t == 0) {
        int s = 0;
        for (int i = 0; i < 16; ++i) { o[i] = s; s += c[i]; }
        int nt = 0;
        for (int i = 0; i < 16; ++i) {
            for (int r0 = 0; r0 < c[i]; r0 += 32) {
                meta[33 + nt] = i;
                meta[53 + nt] = o[i] + r0;
                int rem = c[i] - r0;
                meta[73 + nt] = rem < 32 ? rem : 32;
                ++nt;
            }
        }
        meta[32] = nt;
        for (int k = nt; k < 20; ++k) { meta[33 + k] = 0; meta[53 + k] = 0; meta[73 + k] = 0; }
        float s2 = 0.f;
        for (int i = 0; i < 16; ++i) s2 += tail[1 + i] * tail[17 + i];
        tail[0] = 16.0f * s2;
    }
    __syncthreads();
    if (t < 128) perm[o[e] + pos[t]] = t;
    if (t < 16) { meta[t] = c[t]; meta[16 + t] = o[t]; }
}

// ---------- expert layer 1 ----------
__global__ __launch_bounds__(64) void k_mlp1(
    const ushort_t* __restrict__ zb, const int* __restrict__ meta, const int* __restrict__ perm,
    const float* __restrict__ w1, const float* __restrict__ b1, ushort_t* __restrict__ h1b)
{
    const int ty = blockIdx.y;
    if (ty >= meta[32]) return;
    const int e = meta[33 + ty], ts = meta[53 + ty], rows = meta[73 + ty];
    const int n0 = blockIdx.x * 32;
    __shared__ __align__(16) ushort_t ws[32 * 520];
    __shared__ int tks[32];
    const int lane = threadIdx.x;
    const int mn = lane & 31, g = lane >> 5;

    if (lane < 32) tks[lane] = (lane < rows) ? perm[ts + lane] : -1;

    const float* Wg = w1 + ((size_t)e << 18) + n0;
    {
        const int cq = lane & 7, dg = lane >> 3;
        #pragma unroll 4
        for (int it = 0; it < 32; ++it) {
            int d = it * 16 + dg * 2;
            float4 va = *(const float4*)(Wg + (size_t)d * 512 + 4 * cq);
            float4 vb = *(const float4*)(Wg + (size_t)(d + 1) * 512 + 4 * cq);
            *(unsigned*)&ws[(4 * cq + 0) * 520 + d] = pk2bf(va.x, vb.x);
            *(unsigned*)&ws[(4 * cq + 1) * 520 + d] = pk2bf(va.y, vb.y);
            *(unsigned*)&ws[(4 * cq + 2) * 520 + d] = pk2bf(va.z, vb.z);
            *(unsigned*)&ws[(4 * cq + 3) * 520 + d] = pk2bf(va.w, vb.w);
        }
    }
    __syncthreads();

    const int tok_a = tks[mn] < 0 ? 0 : tks[mn];
    const ushort_t* za = zb + (size_t)tok_a * 512;

    f32x16 acc;
    #pragma unroll
    for (int i = 0; i < 16; ++i) acc[i] = 0.f;

    #pragma unroll 4
    for (int kt = 0; kt < 16; ++kt) {
        int k0 = kt * 32;
        short8 a0 = *(const short8*)(za + k0 + g * 8);
        short8 a1 = *(const short8*)(za + k0 + 16 + g * 8);
        short8 b0 = *(const short8*)(&ws[mn * 520 + k0 + g * 8]);
        short8 b1 = *(const short8*)(&ws[mn * 520 + k0 + 16 + g * 8]);
        acc = MFMA32(a0, b0, acc);
        acc = MFMA32(a1, b1, acc);
    }

    const float bias = b1[e * 512 + n0 + mn];
    #pragma unroll
    for (int r = 0; r < 16; ++r) {
        int mrow = (r & 3) + 8 * (r >> 2) + 4 * g;
        int tok = tks[mrow];
        if (tok >= 0) {
            float v = fmaxf(acc[r] + bias, 0.f);
            h1b[(size_t)tok * 512 + n0 + mn] = f2bf(v);
        }
    }
}

// ---------- expert layer 2 ----------
__global__ __launch_bounds__(64) void k_mlp2(
    const ushort_t* __restrict__ h1b, const int* __restrict__ meta, const int* __restrict__ perm,
    const float* __restrict__ w2, const float* __restrict__ b2, float* __restrict__ out)
{
    const int ty = blockIdx.y;
    if (ty >= meta[32]) return;
    const int e = meta[33 + ty], ts = meta[53 + ty], rows = meta[73 + ty];
    const int n0 = blockIdx.x * 32;
    __shared__ __align__(16) ushort_t ws[32 * 520];
    __shared__ int tks[32];
    const int lane = threadIdx.x;
    const int mn = lane & 31, g = lane >> 5;

    if (lane < 32) tks[lane] = (lane < rows) ? perm[ts + lane] : -1;

    const float* Wg = w2 + (size_t)e * 512000 + n0;
    {
        const int cq = lane & 7, dg = lane >> 3;
        const bool cut = (n0 == 992) && (cq >= 2);
        #pragma unroll 4
        for (int it = 0; it < 32; ++it) {
            int d = it * 16 + dg * 2;
            float4 va = make_float4(0.f, 0.f, 0.f, 0.f), vb = va;
            if (!cut) {
                va = *(const float4*)(Wg + (size_t)d * 1000 + 4 * cq);
                vb = *(const float4*)(Wg + (size_t)(d + 1) * 1000 + 4 * cq);
            }
            *(unsigned*)&ws[(4 * cq + 0) * 520 + d] = pk2bf(va.x, vb.x);
            *(unsigned*)&ws[(4 * cq + 1) * 520 + d] = pk2bf(va.y, vb.y);
            *(unsigned*)&ws[(4 * cq + 2) * 520 + d] = pk2bf(va.z, vb.z);
            *(unsigned*)&ws[(4 * cq + 3) * 520 + d] = pk2bf(va.w, vb.w);
        }
    }
    __syncthreads();

    const int tok_a = tks[mn] < 0 ? 0 : tks[mn];
    const ushort_t* ha = h1b + (size_t)tok_a * 512;

    f32x16 acc;
    #pragma unroll
    for (int i = 0; i < 16; ++i) acc[i] = 0.f;

    #pragma unroll 4
    for (int kt = 0; kt < 16; ++kt) {
        int k0 = kt * 32;
        short8 a0 = *(const short8*)(ha + k0 + g * 8);
        short8 a1 = *(const short8*)(ha + k0 + 16 + g * 8);
        short8 b0 = *(const short8*)(&ws[mn * 520 + k0 + g * 8]);
        short8 b1 = *(const short8*)(&ws[mn * 520 + k0 + 16 + g * 8]);
        acc = MFMA32(a0, b0, acc);
        acc = MFMA32(a1, b1, acc);
    }

    const int colo = n0 + mn;
    if (colo < 1000) {
        const float bias = b2[e * 1000 + colo];
        #pragma unroll
        for (int r = 0; r < 16; ++r) {
            int mrow = (r & 3) + 8 * (r >> 2) + 4 * g;
            int tok = tks[mrow];
            if (tok >= 0)
                out[(size_t)tok * 1000 + colo] = acc[r] + bias;
        }
    }
}

extern "C" void kernel_launch(void* const* d_in, const int* in_sizes, int n_in,
                              void* d_out, int out_size, void* d_ws, size_t ws_size,
                              hipStream_t stream)
{
    const float* x   = (const float*)d_in[0];
    const float* c1w = (const float*)d_in[1];
    const float* c1b = (const float*)d_in[2];
    const float* c2w = (const float*)d_in[3];
    const float* c2b = (const float*)d_in[4];
    const float* c3w = (const float*)d_in[5];
    const float* c3b = (const float*)d_in[6];
    const float* c4w = (const float*)d_in[7];
    const float* c4b = (const float*)d_in[8];
    const float* pw  = (const float*)d_in[9];
    const float* pb  = (const float*)d_in[10];
    const float* rw  = (const float*)d_in[11];
    const float* rb  = (const float*)d_in[12];
    const float* w1  = (const float*)d_in[13];
    const float* b1  = (const float*)d_in[14];
    const float* w2  = (const float*)d_in[15];
    const float* b2  = (const float*)d_in[16];

    float* out = (float*)d_out;
    float* tail = out + 128000;   // aux, counts[16], importance[16]

    char* w = (char*)d_ws;
    ushort_t* a2   = (ushort_t*)(w);                  // 33554432 B
    ushort_t* a3   = (ushort_t*)(w + 33554432);       // 16777216 B
    ushort_t* w2f  = (ushort_t*)(w + 50331648);       // 18432 B
    ushort_t* w3f  = (ushort_t*)(w + 50350080);       // 36864 B
    ushort_t* w4f  = (ushort_t*)(w + 50386944);       // 73728 B
    ushort_t* c1f  = (ushort_t*)(w + 50460672);       // 3072 B
    float*    feat = (float*)(w + 50464768);          // 32768 B
    ushort_t* zb   = (ushort_t*)(w + 50497536);       // 131072 B
    ushort_t* h1b  = (ushort_t*)(w + 50628608);       // 131072 B
    int*      top1 = (int*)(w + 50759680);            // 512 B
    int*      meta = (int*)(w + 50760192);            // 512 B
    int*      perm = (int*)(w + 50760704);            // 512 B

    k_wcvt  <<<34, 256, 0, stream>>>(c1w, c2w, c3w, c4w, c1f, w2f, w3f, w4f, feat, tail);
    k_c12   <<<dim3(8, 8, 128), 512, 0, stream>>>(x, c1f, c1b, w2f, c2b, a2);
    k_c3    <<<dim3(4, 4, 128), 512, 0, stream>>>(a2, w3f, c3b, a3);
    k_c4    <<<dim3(2, 2, 128), 512, 0, stream>>>(a3, w4f, c4b, feat);
    k_router<<<128, 256, 0, stream>>>(feat, pw, pb, rw, rb, zb, top1, tail);
    k_sort  <<<1, 128, 0, stream>>>(top1, meta, perm, tail);
    k_mlp1  <<<dim3(16, 20), 64, 0, stream>>>(zb, meta, perm, w1, b1, h1b);
    k_mlp2  <<<dim3(32, 20), 64, 0, stream>>>(h1b, meta, perm, w2, b2, out);
}

// Round 10
// 203.120 us; speedup vs baseline: 1.0457x; 1.0457x over previous
//
#include <hip/hip_runtime.h>
#include <math.h>

typedef unsigned short ushort_t;
typedef short short4x __attribute__((ext_vector_type(4)));
typedef short short8 __attribute__((ext_vector_type(8)));
typedef float f32x16 __attribute__((ext_vector_type(16)));

#define MFMA32(A,B,C) __builtin_amdgcn_mfma_f32_32x32x16_bf16(A,B,C,0,0,0)

__device__ __forceinline__ ushort_t f2bf(float f) {
    union { float f; unsigned u; } c; c.f = f;
    unsigned u = c.u;
    unsigned r = (u + 0x7FFFu + ((u >> 16) & 1u)) >> 16;
    return (ushort_t)r;
}

__device__ __forceinline__ unsigned pk2bf(float lo, float hi) {
    unsigned r;
    asm("v_cvt_pk_bf16_f32 %0, %1, %2" : "=v"(r) : "v"(lo), "v"(hi));
    return r;
}

// ---------- weight repack + output-scalar zeroing ----------
// conv2/3/4: kappa(g,j) = g*8+j within each K=16 slice.
// conv1: kappa k = pixel*4 + channel (pixel = ky*3+kx, 9 real + 3 dummy; ch 3 = pad)
__global__ __launch_bounds__(256) void k_wcvt(
    const float* __restrict__ c1w, const float* __restrict__ c2w,
    const float* __restrict__ c3w, const float* __restrict__ c4w,
    ushort_t* __restrict__ c1f, ushort_t* __restrict__ w2f,
    ushort_t* __restrict__ w3f, ushort_t* __restrict__ w4f,
    float* __restrict__ feat, float* __restrict__ tail)
{
    if (blockIdx.x == 33) {   // zero feat + tail (replaces memsets)
        for (int i = threadIdx.x; i < 8192; i += 256) feat[i] = 0.f;
        if (threadIdx.x < 33) tail[threadIdx.x] = 0.f;
        return;
    }
    int r = blockIdx.x * 256 + threadIdx.x;
    int lane = r & 63, m = lane & 31, g = (lane >> 5) & 1;
    if (r < 1152) {                       // conv2: f = tau*2+h
        int f = r >> 6, tau = f >> 1, h = f & 1, ky = tau / 3, kx = tau % 3;
        #pragma unroll
        for (int j = 0; j < 8; ++j) {
            int ic = h * 16 + g * 8 + j;
            w2f[r * 8 + j] = f2bf(c2w[((m * 32 + ic) * 3 + ky) * 3 + kx]);
        }
    } else if (r < 3456) {                // conv3: f = ot*18 + tau*2 + h
        int rr = r - 1152;
        int f = rr >> 6;
        int ot = f / 18, fl = f % 18, tau = fl >> 1, h = fl & 1, ky = tau / 3, kx = tau % 3;
        int oc = ot * 32 + m;
        #pragma unroll
        for (int j = 0; j < 8; ++j) {
            int ic = h * 16 + g * 8 + j;
            w3f[rr * 8 + j] = f2bf(c3w[((oc * 32 + ic) * 3 + ky) * 3 + kx]);
        }
    } else if (r < 8064) {                // conv4: f = ot*36 + tau*4 + h
        int rr = r - 3456;
        int f = rr >> 6;
        int ot = f / 36, fl = f % 36, tau = fl >> 2, h = fl & 3, ky = tau / 3, kx = tau % 3;
        int oc = ot * 32 + m;
        #pragma unroll
        for (int j = 0; j < 8; ++j) {
            int ic = h * 16 + g * 8 + j;
            w4f[rr * 8 + j] = f2bf(c4w[((oc * 64 + ic) * 3 + ky) * 3 + kx]);
        }
    } else if (r < 8256) {                // conv1: 3 frags, k = p*4 + c (K=48)
        int rr = r - 8064;                // 0..191
        int f = rr >> 6;                  // 0..2
        #pragma unroll
        for (int j = 0; j < 8; ++j) {
            int k = f * 16 + g * 8 + j;
            int p = k >> 2, c = k & 3;
            ushort_t v = 0;
            if (p < 9 && c < 3)
                v = f2bf(c1w[(m * 3 + c) * 9 + p]);
            c1f[rr * 8 + j] = v;
        }
    }
}

// ---------- K_A: conv1 (MFMA32) + conv2 (MFMA32) + relu + pool -> a2 bf16 NHWC [128][64][64][32]
// grid (8,8,128): tile = 16x16 conv2 outputs. 8 waves, wave w -> rows 2w,2w+1.
// a1s cells are 5x16B slots; data slots XOR-swizzled by m(cell)=(cell>>3)&3 (bank de-alias).
__global__ __launch_bounds__(512, 4) void k_c12(
    const float* __restrict__ x,
    const ushort_t* __restrict__ c1f, const float* __restrict__ c1b,
    const ushort_t* __restrict__ w2f, const float* __restrict__ c2b,
    ushort_t* __restrict__ a2)
{
    __shared__ __align__(16) ushort_t xs[1600];        // x tile [20][20][4] (c fastest, pad)
    __shared__ __align__(16) ushort_t a1s[324 * 40];   // 18x18 cells, 32 ic + 8 pad
    __shared__ float c2bs[32], c1bs[32];
    const int t = threadIdx.x;
    const int bx = blockIdx.x, by = blockIdx.y, b = blockIdx.z;
    const int ox0 = bx * 16, oy0 = by * 16;

    if (t < 32) { c2bs[t] = c2b[t]; c1bs[t] = c1b[t]; }
    for (int i = t; i < 400; i += 512) {
        int yy = i / 20, xx = i % 20;
        int gy = oy0 - 2 + yy, gx = ox0 - 2 + xx;
        float v0 = 0.f, v1 = 0.f, v2 = 0.f;
        if (gy >= 0 && gy < 128 && gx >= 0 && gx < 128) {
            const float* px = x + ((size_t)(b * 3) * 128 + gy) * 128 + gx;
            v0 = px[0]; v1 = px[16384]; v2 = px[32768];
        }
        uint2 pk;
        pk.x = pk2bf(v0, v1);
        pk.y = pk2bf(v2, 0.f);
        *(uint2*)&xs[i * 4] = pk;
    }

    const int wave = t >> 6, lane = t & 63;
    const int n = lane & 31, g = lane >> 5;

    short8 a1f0 = *(const short8*)(c1f + lane * 8);
    short8 a1f1 = *(const short8*)(c1f + (64 + lane) * 8);
    short8 a1f2 = *(const short8*)(c1f + (128 + lane) * 8);
    __syncthreads();

    // per-lane conv1 bias (row mapping: oc = 8*qd + 4*g + jj)
    float cb1[16];
    #pragma unroll
    for (int qd = 0; qd < 4; ++qd)
        #pragma unroll
        for (int jj = 0; jj < 4; ++jj)
            cb1[qd * 4 + jj] = c1bs[qd * 8 + 4 * g + jj];

    // ---- conv1 via MFMA32 over 11 groups of 32 halo cells (324) ----
    for (int grp = wave; grp < 11; grp += 8) {
        int q = grp * 32 + n;
        bool qv = q < 324;
        int qc = qv ? q : 0;
        int cy = qc / 18, cx = qc % 18;
        int gy = oy0 - 1 + cy, gx = ox0 - 1 + cx;
        bool inimg = qv && gy >= 0 && gy < 128 && gx >= 0 && gx < 128;
        int base = (cy * 20 + cx) * 4;

        short4x q0 = *(const short4x*)&xs[base + (g ? 8 : 0)];
        short4x q1 = *(const short4x*)&xs[base + (g ? 80 : 4)];
        short4x q2 = *(const short4x*)&xs[base + (g ? 160 : 84)];
        short4x q3 = *(const short4x*)&xs[base + (g ? 164 : 88)];
        short4x q4 = *(const short4x*)&xs[base + 168];

        short8 b0 = __builtin_shufflevector(q0, q1, 0, 1, 2, 3, 4, 5, 6, 7);
        short8 b1 = __builtin_shufflevector(q2, q3, 0, 1, 2, 3, 4, 5, 6, 7);
        short8 b2 = __builtin_shufflevector(q4, q4, 0, 1, 2, 3, 0, 1, 2, 3);

        f32x16 acc;
        #pragma unroll
        for (int i = 0; i < 16; ++i) acc[i] = 0.f;
        acc = MFMA32(a1f0, b0, acc);
        acc = MFMA32(a1f1, b1, acc);
        acc = MFMA32(a1f2, b2, acc);

        if (qv) {
            const int mq = (q >> 3) & 3;          // slot swizzle
            ushort_t* cellp = &a1s[q * 40 + 4 * g];
            #pragma unroll
            for (int qd = 0; qd < 4; ++qd) {
                float v0 = fmaxf(acc[qd * 4 + 0] + cb1[qd * 4 + 0], 0.f);
                float v1 = fmaxf(acc[qd * 4 + 1] + cb1[qd * 4 + 1], 0.f);
                float v2 = fmaxf(acc[qd * 4 + 2] + cb1[qd * 4 + 2], 0.f);
                float v3 = fmaxf(acc[qd * 4 + 3] + cb1[qd * 4 + 3], 0.f);
                uint2 pk;
                pk.x = inimg ? pk2bf(v0, v1) : 0u;
                pk.y = inimg ? pk2bf(v2, v3) : 0u;
                *(uint2*)&cellp[8 * (qd ^ mq)] = pk;
            }
        }
    }
    __syncthreads();

    // ---- conv2 via MFMA32 ----
    const int ry = n >> 4, rx = n & 15;
    const int y2 = wave * 2 + ry;

    short8 af[18];
    #pragma unroll
    for (int f = 0; f < 18; ++f)
        af[f] = *(const short8*)(w2f + (f * 64 + lane) * 8);

    f32x16 acc;
    #pragma unroll
    for (int i = 0; i < 16; ++i) acc[i] = 0.f;

    #pragma unroll
    for (int tau = 0; tau < 9; ++tau) {
        int dy = tau / 3, dx = tau % 3;
        int cell = (y2 + dy) * 18 + (rx + dx);
        int mq = (cell >> 3) & 3;
        const ushort_t* bb = &a1s[cell * 40];
        int o0 = (g ^ mq) * 8;
        short8 b0 = *(const short8*)(bb + o0);
        short8 b1 = *(const short8*)(bb + (o0 ^ 16));
        acc = MFMA32(af[tau * 2 + 0], b0, acc);
        acc = MFMA32(af[tau * 2 + 1], b1, acc);
    }

    const int opy = by * 8 + wave;
    const int opx = bx * 8 + (rx >> 1);
    float pv[16];
    #pragma unroll
    for (int r = 0; r < 16; ++r) {
        float v = fmaxf(acc[r] + c2bs[(r & 3) + 8 * (r >> 2) + 4 * g], 0.f);
        v += __shfl_xor(v, 1);
        v += __shfl_xor(v, 16);
        pv[r] = v * 0.25f;
    }
    if ((lane & 17) == 0) {
        ushort_t* dst = &a2[(((size_t)b * 64 + opy) * 64 + opx) * 32 + 4 * g];
        #pragma unroll
        for (int qd = 0; qd < 4; ++qd) {
            uint2 pk;
            pk.x = pk2bf(pv[qd * 4 + 0], pv[qd * 4 + 1]);
            pk.y = pk2bf(pv[qd * 4 + 2], pv[qd * 4 + 3]);
            *(uint2*)&dst[8 * qd] = pk;
        }
    }
}

// ---------- K_B: conv3 (MFMA32, dual oc-tile) + relu + pool -> a3 bf16 NHWC [128][32][32][64]
// grid (4,4,128), 512 thr: tile 16x16. Same slot swizzle on s[].
__global__ __launch_bounds__(512, 4) void k_c3(
    const ushort_t* __restrict__ a2, const ushort_t* __restrict__ w3f,
    const float* __restrict__ c3b, ushort_t* __restrict__ a3)
{
    __shared__ __align__(16) ushort_t s[324 * 40];   // 18x18 cells
    __shared__ float bs[64];
    const int t = threadIdx.x;
    const int bx = blockIdx.x, by = blockIdx.y, b = blockIdx.z;
    const int x0 = bx * 16, y0 = by * 16;
    if (t < 64) bs[t] = c3b[t];
    for (int idx = t; idx < 1296; idx += 512) {
        int cell = idx >> 2, part = idx & 3;
        int cy = cell / 18, cx = cell % 18;
        int gy = y0 - 1 + cy, gx = x0 - 1 + cx;
        uint4 v = make_uint4(0, 0, 0, 0);
        if (gy >= 0 && gy < 64 && gx >= 0 && gx < 64)
            v = *(const uint4*)(a2 + (((size_t)b * 64 + gy) * 64 + gx) * 32 + part * 8);
        int mq = (cell >> 3) & 3;
        *(uint4*)(&s[cell * 40 + (part ^ mq) * 8]) = v;
    }
    __syncthreads();

    const int wave = t >> 6, lane = t & 63;
    const int n = lane & 31, g = lane >> 5;
    const int ry = n >> 4, rx = n & 15;
    const int y3 = wave * 2 + ry;

    f32x16 acc0, acc1;
    #pragma unroll
    for (int i = 0; i < 16; ++i) { acc0[i] = 0.f; acc1[i] = 0.f; }

    #pragma unroll
    for (int tau = 0; tau < 9; ++tau) {
        int dy = tau / 3, dx = tau % 3;
        int cell = (y3 + dy) * 18 + (rx + dx);
        int mq = (cell >> 3) & 3;
        const ushort_t* bb = &s[cell * 40];
        int o0 = (g ^ mq) * 8;
        short8 b0 = *(const short8*)(bb + o0);
        short8 b1 = *(const short8*)(bb + (o0 ^ 16));
        short8 a00 = *(const short8*)(w3f + ((tau * 2 + 0) * 64 + lane) * 8);
        short8 a01 = *(const short8*)(w3f + ((tau * 2 + 1) * 64 + lane) * 8);
        short8 a10 = *(const short8*)(w3f + (((18 + tau * 2) + 0) * 64 + lane) * 8);
        short8 a11 = *(const short8*)(w3f + (((18 + tau * 2) + 1) * 64 + lane) * 8);
        acc0 = MFMA32(a00, b0, acc0);
        acc0 = MFMA32(a01, b1, acc0);
        acc1 = MFMA32(a10, b0, acc1);
        acc1 = MFMA32(a11, b1, acc1);
    }

    const int opy = by * 8 + wave;
    const int opx = bx * 8 + (rx >> 1);
    ushort_t* dst = &a3[(((size_t)b * 32 + opy) * 32 + opx) * 64 + 4 * g];
    #pragma unroll
    for (int ot = 0; ot < 2; ++ot) {
        const f32x16& ac = ot ? acc1 : acc0;
        float pv[16];
        #pragma unroll
        for (int r = 0; r < 16; ++r) {
            float v = fmaxf(ac[r] + bs[ot * 32 + (r & 3) + 8 * (r >> 2) + 4 * g], 0.f);
            v += __shfl_xor(v, 1);
            v += __shfl_xor(v, 16);
            pv[r] = v * 0.25f;
        }
        if ((lane & 17) == 0) {
            #pragma unroll
            for (int qd = 0; qd < 4; ++qd) {
                uint2 pk;
                pk.x = pk2bf(pv[qd * 4 + 0], pv[qd * 4 + 1]);
                pk.y = pk2bf(pv[qd * 4 + 2], pv[qd * 4 + 3]);
                *(uint2*)&dst[ot * 32 + 8 * qd] = pk;
            }
        }
    }
}

// ---------- K_C: conv4 (MFMA32, dual oc-tile) + relu + global mean -> feat f32 [128][64]
// grid (2,2,128), 512 thr: tile 16x16. 8 data slots/cell, swizzled.
__global__ __launch_bounds__(512, 2) void k_c4(
    const ushort_t* __restrict__ a3, const ushort_t* __restrict__ w4f,
    const float* __restrict__ c4b, float* __restrict__ feat)
{
    __shared__ __align__(16) ushort_t s[324 * 72];   // 18x18 cells, 64 ic + 8 pad
    __shared__ float bs[64];
    const int t = threadIdx.x;
    const int bx = blockIdx.x, by = blockIdx.y, b = blockIdx.z;
    const int x0 = bx * 16, y0 = by * 16;
    if (t < 64) bs[t] = c4b[t];
    for (int idx = t; idx < 2592; idx += 512) {
        int cell = idx >> 3, part = idx & 7;
        int cy = cell / 18, cx = cell % 18;
        int gy = y0 - 1 + cy, gx = x0 - 1 + cx;
        uint4 v = make_uint4(0, 0, 0, 0);
        if (gy >= 0 && gy < 32 && gx >= 0 && gx < 32)
            v = *(const uint4*)(a3 + (((size_t)b * 32 + gy) * 32 + gx) * 64 + part * 8);
        int mq = (cell >> 3) & 3;
        *(uint4*)(&s[cell * 72 + (part ^ mq) * 8]) = v;
    }
    __syncthreads();

    const int wave = t >> 6, lane = t & 63;
    const int n = lane & 31, g = lane >> 5;
    const int ry = n >> 4, rx = n & 15;
    const int y4 = wave * 2 + ry;

    f32x16 acc0, acc1;
    #pragma unroll
    for (int i = 0; i < 16; ++i) { acc0[i] = 0.f; acc1[i] = 0.f; }

    #pragma unroll
    for (int hp = 0; hp < 2; ++hp) {
        #pragma unroll
        for (int tau = 0; tau < 9; ++tau) {
            int dy = tau / 3, dx = tau % 3;
            int cell = (y4 + dy) * 18 + (rx + dx);
            int mq = (cell >> 3) & 3;
            const ushort_t* bb = &s[cell * 72];
            int o0 = ((4 * hp + g) ^ mq) * 8;
            short8 b0 = *(const short8*)(bb + o0);
            short8 b1 = *(const short8*)(bb + (o0 ^ 16));
            short8 a00 = *(const short8*)(w4f + ((tau * 4 + hp * 2 + 0) * 64 + lane) * 8);
            short8 a01 = *(const short8*)(w4f + ((tau * 4 + hp * 2 + 1) * 64 + lane) * 8);
            short8 a10 = *(const short8*)(w4f + ((36 + tau * 4 + hp * 2 + 0) * 64 + lane) * 8);
            short8 a11 = *(const short8*)(w4f + ((36 + tau * 4 + hp * 2 + 1) * 64 + lane) * 8);
            acc0 = MFMA32(a00, b0, acc0);
            acc0 = MFMA32(a01, b1, acc0);
            acc1 = MFMA32(a10, b0, acc1);
            acc1 = MFMA32(a11, b1, acc1);
        }
    }

    #pragma unroll
    for (int ot = 0; ot < 2; ++ot) {
        const f32x16& ac = ot ? acc1 : acc0;
        #pragma unroll
        for (int r = 0; r < 16; ++r) {
            int oc = ot * 32 + (r & 3) + 8 * (r >> 2) + 4 * g;
            float v = fmaxf(ac[r] + bs[oc], 0.f);
            v += __shfl_xor(v, 1);
            v += __shfl_xor(v, 2);
            v += __shfl_xor(v, 4);
            v += __shfl_xor(v, 8);
            v += __shfl_xor(v, 16);
            if ((lane & 31) == 0)
                atomicAdd(&feat[b * 64 + oc], v * (1.0f / 1024.0f));
        }
    }
}

// ---------- router ----------
__global__ __launch_bounds__(256) void k_router(
    const float* __restrict__ meanacc,
    const float* __restrict__ pw, const float* __restrict__ pb,
    const float* __restrict__ rw, const float* __restrict__ rb,
    ushort_t* __restrict__ zb, int* __restrict__ top1, float* __restrict__ tail)
{
    __shared__ float m[64];
    __shared__ float zs[512];
    __shared__ float part[256];
    __shared__ float gate[16];
    const int b = blockIdx.x, t = threadIdx.x;
    if (t < 64) m[t] = meanacc[b * 64 + t];
    __syncthreads();

    #pragma unroll
    for (int j = 0; j < 2; ++j) {
        int d = t + j * 256;
        float s = pb[d];
        for (int c = 0; c < 64; ++c) s += m[c] * pw[c * 512 + d];
        zs[d] = s;
        zb[b * 512 + d] = f2bf(s);
    }
    __syncthreads();
    {
        int e = t & 15, gg = t >> 4;
        float s = 0.f;
        for (int j = 0; j < 32; ++j) {
            int d = gg * 32 + j;
            s += zs[d] * rw[d * 16 + e];
        }
        part[t] = s;
    }
    __syncthreads();
    if (t < 16) {
        float s = rb[t];
        for (int gg = 0; gg < 16; ++gg) s += part[gg * 16 + t];
        gate[t] = s;
    }
    __syncthreads();
    if (t == 0) {
        float mx = gate[0];
        int am = 0;
        for (int e = 1; e < 16; ++e)
            if (gate[e] > mx) { mx = gate[e]; am = e; }
        float pr[16];
        float sum = 0.f;
        for (int e = 0; e < 16; ++e) { pr[e] = expf(gate[e] - mx); sum += pr[e]; }
        float inv = 1.f / sum;
        top1[b] = am;
        atomicAdd(&tail[1 + am], 1.0f / 128.0f);
        for (int e = 0; e < 16; ++e)
            atomicAdd(&tail[17 + e], pr[e] * inv * (1.0f / 128.0f));
    }
}

// ---------- token sort + padded 32-row tile list + aux ----------
__global__ void k_sort(const int* __restrict__ top1, int* __restrict__ meta,
                       int* __restrict__ perm, float* __restrict__ tail)
{
    __shared__ int c[16], o[16], pos[128];
    const int t = threadIdx.x;
    if (t < 16) c[t] = 0;
    __syncthreads();
    int e = 0;
    if (t < 128) { e = top1[t]; pos[t] = atomicAdd(&c[e], 1); }
    __syncthreads();
    if (t == 0) {
        int s = 0;
        for (int i = 0; i < 16; ++i) { o[i] = s; s += c[i]; }
        int nt = 0;
        for (int i = 0; i < 16; ++i) {
            for (int r0 = 0; r0 < c[i]; r0 += 32) {
                meta[33 + nt] = i;
                meta[53 + nt] = o[i] + r0;
                int rem = c[i] - r0;
                meta[73 + nt] = rem < 32 ? rem : 32;
                ++nt;
            }
        }
        meta[32] = nt;
        for (int k = nt; k < 20; ++k) { meta[33 + k] = 0; meta[53 + k] = 0; meta[73 + k] = 0; }
        float s2 = 0.f;
        for (int i = 0; i < 16; ++i) s2 += tail[1 + i] * tail[17 + i];
        tail[0] = 16.0f * s2;
    }
    __syncthreads();
    if (t < 128) perm[o[e] + pos[t]] = t;
    if (t < 16) { meta[t] = c[t]; meta[16 + t] = o[t]; }
}

// ---------- expert layer 1: h1 = relu(z @ w1[e] + b1) ----------
__global__ __launch_bounds__(64) void k_mlp1(
    const ushort_t* __restrict__ zb, const int* __restrict__ meta, const int* __restrict__ perm,
    const float* __restrict__ w1, const float* __restrict__ b1, ushort_t* __restrict__ h1b)
{
    const int ty = blockIdx.y;
    if (ty >= meta[32]) return;
    const int e = meta[33 + ty], ts = meta[53 + ty], rows = meta[73 + ty];
    const int n0 = blockIdx.x * 32;
    __shared__ __align__(16) ushort_t ws[32 * 520];
    __shared__ int tks[32];
    const int lane = threadIdx.x;
    const int mn = lane & 31, g = lane >> 5;

    if (lane < 32) tks[lane] = (lane < rows) ? perm[ts + lane] : -1;

    const float* Wg = w1 + ((size_t)e << 18) + n0;
    {
        const int cq = lane & 7, dg = lane >> 3;
        #pragma unroll 4
        for (int it = 0; it < 32; ++it) {
            int d = it * 16 + dg * 2;
            float4 va = *(const float4*)(Wg + (size_t)d * 512 + 4 * cq);
            float4 vb = *(const float4*)(Wg + (size_t)(d + 1) * 512 + 4 * cq);
            *(unsigned*)&ws[(4 * cq + 0) * 520 + d] = pk2bf(va.x, vb.x);
            *(unsigned*)&ws[(4 * cq + 1) * 520 + d] = pk2bf(va.y, vb.y);
            *(unsigned*)&ws[(4 * cq + 2) * 520 + d] = pk2bf(va.z, vb.z);
            *(unsigned*)&ws[(4 * cq + 3) * 520 + d] = pk2bf(va.w, vb.w);
        }
    }
    __syncthreads();

    const int tok_a = tks[mn] < 0 ? 0 : tks[mn];
    const ushort_t* za = zb + (size_t)tok_a * 512;

    f32x16 acc;
    #pragma unroll
    for (int i = 0; i < 16; ++i) acc[i] = 0.f;

    #pragma unroll 4
    for (int kt = 0; kt < 16; ++kt) {
        int k0 = kt * 32;
        short8 a0 = *(const short8*)(za + k0 + g * 8);
        short8 a1 = *(const short8*)(za + k0 + 16 + g * 8);
        short8 b0 = *(const short8*)(&ws[mn * 520 + k0 + g * 8]);
        short8 b1 = *(const short8*)(&ws[mn * 520 + k0 + 16 + g * 8]);
        acc = MFMA32(a0, b0, acc);
        acc = MFMA32(a1, b1, acc);
    }

    const float bias = b1[e * 512 + n0 + mn];
    #pragma unroll
    for (int r = 0; r < 16; ++r) {
        int mrow = (r & 3) + 8 * (r >> 2) + 4 * g;
        int tok = tks[mrow];
        if (tok >= 0) {
            float v = fmaxf(acc[r] + bias, 0.f);
            h1b[(size_t)tok * 512 + n0 + mn] = f2bf(v);
        }
    }
}

// ---------- expert layer 2: out = h1 @ w2[e] + b2 ----------
__global__ __launch_bounds__(64) void k_mlp2(
    const ushort_t* __restrict__ h1b, const int* __restrict__ meta, const int* __restrict__ perm,
    const float* __restrict__ w2, const float* __restrict__ b2, float* __restrict__ out)
{
    const int ty = blockIdx.y;
    if (ty >= meta[32]) return;
    const int e = meta[33 + ty], ts = meta[53 + ty], rows = meta[73 + ty];
    const int n0 = blockIdx.x * 32;
    __shared__ __align__(16) ushort_t ws[32 * 520];
    __shared__ int tks[32];
    const int lane = threadIdx.x;
    const int mn = lane & 31, g = lane >> 5;

    if (lane < 32) tks[lane] = (lane < rows) ? perm[ts + lane] : -1;

    const float* Wg = w2 + (size_t)e * 512000 + n0;
    {
        const int cq = lane & 7, dg = lane >> 3;
        const bool cut = (n0 == 992) && (cq >= 2);
        #pragma unroll 4
        for (int it = 0; it < 32; ++it) {
            int d = it * 16 + dg * 2;
            float4 va = make_float4(0.f, 0.f, 0.f, 0.f), vb = va;
            if (!cut) {
                va = *(const float4*)(Wg + (size_t)d * 1000 + 4 * cq);
                vb = *(const float4*)(Wg + (size_t)(d + 1) * 1000 + 4 * cq);
            }
            *(unsigned*)&ws[(4 * cq + 0) * 520 + d] = pk2bf(va.x, vb.x);
            *(unsigned*)&ws[(4 * cq + 1) * 520 + d] = pk2bf(va.y, vb.y);
            *(unsigned*)&ws[(4 * cq + 2) * 520 + d] = pk2bf(va.z, vb.z);
            *(unsigned*)&ws[(4 * cq + 3) * 520 + d] = pk2bf(va.w, vb.w);
        }
    }
    __syncthreads();

    const int tok_a = tks[mn] < 0 ? 0 : tks[mn];
    const ushort_t* ha = h1b + (size_t)tok_a * 512;

    f32x16 acc;
    #pragma unroll
    for (int i = 0; i < 16; ++i) acc[i] = 0.f;

    #pragma unroll 4
    for (int kt = 0; kt < 16; ++kt) {
        int k0 = kt * 32;
        short8 a0 = *(const short8*)(ha + k0 + g * 8);
        short8 a1 = *(const short8*)(ha + k0 + 16 + g * 8);
        short8 b0 = *(const short8*)(&ws[mn * 520 + k0 + g * 8]);
        short8 b1 = *(const short8*)(&ws[mn * 520 + k0 + 16 + g * 8]);
        acc = MFMA32(a0, b0, acc);
        acc = MFMA32(a1, b1, acc);
    }

    const int col = n0 + mn;
    if (col < 1000) {
        const float bias = b2[e * 1000 + col];
        #pragma unroll
        for (int r = 0; r < 16; ++r) {
            int mrow = (r & 3) + 8 * (r >> 2) + 4 * g;
            int tok = tks[mrow];
            if (tok >= 0)
                out[(size_t)tok * 1000 + col] = acc[r] + bias;
        }
    }
}

extern "C" void kernel_launch(void* const* d_in, const int* in_sizes, int n_in,
                              void* d_out, int out_size, void* d_ws, size_t ws_size,
                              hipStream_t stream)
{
    const float* x   = (const float*)d_in[0];
    const float* c1w = (const float*)d_in[1];
    const float* c1b = (const float*)d_in[2];
    const float* c2w = (const float*)d_in[3];
    const float* c2b = (const float*)d_in[4];
    const float* c3w = (const float*)d_in[5];
    const float* c3b = (const float*)d_in[6];
    const float* c4w = (const float*)d_in[7];
    const float* c4b = (const float*)d_in[8];
    const float* pw  = (const float*)d_in[9];
    const float* pb  = (const float*)d_in[10];
    const float* rw  = (const float*)d_in[11];
    const float* rb  = (const float*)d_in[12];
    const float* w1  = (const float*)d_in[13];
    const float* b1  = (const float*)d_in[14];
    const float* w2  = (const float*)d_in[15];
    const float* b2  = (const float*)d_in[16];

    float* out = (float*)d_out;
    float* tail = out + 128000;   // aux, counts[16], importance[16]

    char* w = (char*)d_ws;
    ushort_t* a2   = (ushort_t*)(w);                  // 33554432 B
    ushort_t* a3   = (ushort_t*)(w + 33554432);       // 16777216 B
    ushort_t* w2f  = (ushort_t*)(w + 50331648);       // 18432 B
    ushort_t* w3f  = (ushort_t*)(w + 50350080);       // 36864 B
    ushort_t* w4f  = (ushort_t*)(w + 50386944);       // 73728 B
    ushort_t* c1f  = (ushort_t*)(w + 50460672);       // 3072 B
    float*    feat = (float*)(w + 50464768);          // 32768 B
    ushort_t* zb   = (ushort_t*)(w + 50497536);       // 131072 B
    ushort_t* h1b  = (ushort_t*)(w + 50628608);       // 131072 B
    int*      top1 = (int*)(w + 50759680);            // 512 B
    int*      meta = (int*)(w + 50760192);            // 512 B
    int*      perm = (int*)(w + 50760704);            // 512 B

    k_wcvt  <<<34, 256, 0, stream>>>(c1w, c2w, c3w, c4w, c1f, w2f, w3f, w4f, feat, tail);
    k_c12   <<<dim3(8, 8, 128), 512, 0, stream>>>(x, c1f, c1b, w2f, c2b, a2);
    k_c3    <<<dim3(4, 4, 128), 512, 0, stream>>>(a2, w3f, c3b, a3);
    k_c4    <<<dim3(2, 2, 128), 512, 0, stream>>>(a3, w4f, c4b, feat);
    k_router<<<128, 256, 0, stream>>>(feat, pw, pb, rw, rb, zb, top1, tail);
    k_sort  <<<1, 128, 0, stream>>>(top1, meta, perm, tail);
    k_mlp1  <<<dim3(16, 20), 64, 0, stream>>>(zb, meta, perm, w1, b1, h1b);
    k_mlp2  <<<dim3(32, 20), 64, 0, stream>>>(h1b, meta, perm, w2, b2, out);
}

// Round 11
// 193.972 us; speedup vs baseline: 1.0950x; 1.0472x over previous
//
#include <hip/hip_runtime.h>
#include <math.h>

typedef unsigned short ushort_t;
typedef short short4x __attribute__((ext_vector_type(4)));
typedef short short8 __attribute__((ext_vector_type(8)));
typedef float f32x16 __attribute__((ext_vector_type(16)));

#define MFMA32(A,B,C) __builtin_amdgcn_mfma_f32_32x32x16_bf16(A,B,C,0,0,0)

__device__ __forceinline__ ushort_t f2bf(float f) {
    union { float f; unsigned u; } c; c.f = f;
    unsigned u = c.u;
    unsigned r = (u + 0x7FFFu + ((u >> 16) & 1u)) >> 16;
    return (ushort_t)r;
}

__device__ __forceinline__ unsigned pk2bf(float lo, float hi) {
    unsigned r;
    asm("v_cvt_pk_bf16_f32 %0, %1, %2" : "=v"(r) : "v"(lo), "v"(hi));
    return r;
}

// v + quad_perm(v): cross-lane add on the VALU pipe (no LDS/ds_swizzle)
// 0xB1 = [1,0,3,2] (xor1), 0x4E = [2,3,0,1] (xor2)
template<int CTRL>
__device__ __forceinline__ float dppadd(float v) {
    int p = __builtin_amdgcn_mov_dpp(__builtin_bit_cast(int, v), CTRL, 0xF, 0xF, true);
    return v + __builtin_bit_cast(float, p);
}

// ---------- weight repack + output-scalar zeroing ----------
__global__ __launch_bounds__(256) void k_wcvt(
    const float* __restrict__ c1w, const float* __restrict__ c2w,
    const float* __restrict__ c3w, const float* __restrict__ c4w,
    ushort_t* __restrict__ c1f, ushort_t* __restrict__ w2f,
    ushort_t* __restrict__ w3f, ushort_t* __restrict__ w4f,
    float* __restrict__ feat, float* __restrict__ tail)
{
    if (blockIdx.x == 33) {
        for (int i = threadIdx.x; i < 8192; i += 256) feat[i] = 0.f;
        if (threadIdx.x < 33) tail[threadIdx.x] = 0.f;
        return;
    }
    int r = blockIdx.x * 256 + threadIdx.x;
    int lane = r & 63, m = lane & 31, g = (lane >> 5) & 1;
    if (r < 1152) {                       // conv2: f = tau*2+h
        int f = r >> 6, tau = f >> 1, h = f & 1, ky = tau / 3, kx = tau % 3;
        #pragma unroll
        for (int j = 0; j < 8; ++j) {
            int ic = h * 16 + g * 8 + j;
            w2f[r * 8 + j] = f2bf(c2w[((m * 32 + ic) * 3 + ky) * 3 + kx]);
        }
    } else if (r < 3456) {                // conv3: f = ot*18 + tau*2 + h
        int rr = r - 1152;
        int f = rr >> 6;
        int ot = f / 18, fl = f % 18, tau = fl >> 1, h = fl & 1, ky = tau / 3, kx = tau % 3;
        int oc = ot * 32 + m;
        #pragma unroll
        for (int j = 0; j < 8; ++j) {
            int ic = h * 16 + g * 8 + j;
            w3f[rr * 8 + j] = f2bf(c3w[((oc * 32 + ic) * 3 + ky) * 3 + kx]);
        }
    } else if (r < 8064) {                // conv4: f = ot*36 + tau*4 + h
        int rr = r - 3456;
        int f = rr >> 6;
        int ot = f / 36, fl = f % 36, tau = fl >> 2, h = fl & 3, ky = tau / 3, kx = tau % 3;
        int oc = ot * 32 + m;
        #pragma unroll
        for (int j = 0; j < 8; ++j) {
            int ic = h * 16 + g * 8 + j;
            w4f[rr * 8 + j] = f2bf(c4w[((oc * 64 + ic) * 3 + ky) * 3 + kx]);
        }
    } else if (r < 8256) {                // conv1: 3 frags, k = p*4 + c (K=48)
        int rr = r - 8064;
        int f = rr >> 6;
        #pragma unroll
        for (int j = 0; j < 8; ++j) {
            int k = f * 16 + g * 8 + j;
            int p = k >> 2, c = k & 3;
            ushort_t v = 0;
            if (p < 9 && c < 3)
                v = f2bf(c1w[(m * 3 + c) * 9 + p]);
            c1f[rr * 8 + j] = v;
        }
    }
}

// ---------- K_A: conv1 (MFMA32) + conv2 (MFMA32, DPP pool) -> a2 bf16 NHWC [128][64][64][32]
// grid (8,8,128), 512 thr. conv2 position map: x=(n>>2)*2+(n&1), y=wave*2+((n>>1)&1)
// so the 2x2 pool quad = lane quad -> DPP-only pooling.
__global__ __launch_bounds__(512, 4) void k_c12(
    const float* __restrict__ x,
    const ushort_t* __restrict__ c1f, const float* __restrict__ c1b,
    const ushort_t* __restrict__ w2f, const float* __restrict__ c2b,
    ushort_t* __restrict__ a2)
{
    __shared__ __align__(16) ushort_t xs[1600];        // [20][20][4] c-fastest
    __shared__ __align__(16) ushort_t a1s[324 * 40];   // 18x18 cells, 5 slots (swizzled)
    __shared__ float c2bs[32], c1bs[32];
    const int t = threadIdx.x;
    const int bx = blockIdx.x, by = blockIdx.y, b = blockIdx.z;
    const int ox0 = bx * 16, oy0 = by * 16;

    if (t < 32) { c2bs[t] = c2b[t]; c1bs[t] = c1b[t]; }
    for (int i = t; i < 400; i += 512) {
        int yy = i / 20, xx = i % 20;
        int gy = oy0 - 2 + yy, gx = ox0 - 2 + xx;
        float v0 = 0.f, v1 = 0.f, v2 = 0.f;
        if (gy >= 0 && gy < 128 && gx >= 0 && gx < 128) {
            const float* px = x + ((size_t)(b * 3) * 128 + gy) * 128 + gx;
            v0 = px[0]; v1 = px[16384]; v2 = px[32768];
        }
        uint2 pk;
        pk.x = pk2bf(v0, v1);
        pk.y = pk2bf(v2, 0.f);
        *(uint2*)&xs[i * 4] = pk;
    }

    const int wave = t >> 6, lane = t & 63;
    const int n = lane & 31, g = lane >> 5;

    short8 a1f0 = *(const short8*)(c1f + lane * 8);
    short8 a1f1 = *(const short8*)(c1f + (64 + lane) * 8);
    short8 a1f2 = *(const short8*)(c1f + (128 + lane) * 8);
    __syncthreads();

    float cb1[16];
    #pragma unroll
    for (int qd = 0; qd < 4; ++qd)
        #pragma unroll
        for (int jj = 0; jj < 4; ++jj)
            cb1[qd * 4 + jj] = c1bs[qd * 8 + 4 * g + jj];

    // ---- conv1 via MFMA32 over 11 groups of 32 halo cells (324) ----
    for (int grp = wave; grp < 11; grp += 8) {
        int q = grp * 32 + n;
        bool qv = q < 324;
        int qc = qv ? q : 0;
        int cy = qc / 18, cx = qc % 18;
        int gy = oy0 - 1 + cy, gx = ox0 - 1 + cx;
        bool inimg = qv && gy >= 0 && gy < 128 && gx >= 0 && gx < 128;
        int base = (cy * 20 + cx) * 4;

        short4x q0 = *(const short4x*)&xs[base + (g ? 8 : 0)];
        short4x q1 = *(const short4x*)&xs[base + (g ? 80 : 4)];
        short4x q2 = *(const short4x*)&xs[base + (g ? 160 : 84)];
        short4x q3 = *(const short4x*)&xs[base + (g ? 164 : 88)];
        short4x q4 = *(const short4x*)&xs[base + 168];

        short8 b0 = __builtin_shufflevector(q0, q1, 0, 1, 2, 3, 4, 5, 6, 7);
        short8 b1 = __builtin_shufflevector(q2, q3, 0, 1, 2, 3, 4, 5, 6, 7);
        short8 b2 = __builtin_shufflevector(q4, q4, 0, 1, 2, 3, 0, 1, 2, 3);

        f32x16 acc;
        #pragma unroll
        for (int i = 0; i < 16; ++i) acc[i] = 0.f;
        acc = MFMA32(a1f0, b0, acc);
        acc = MFMA32(a1f1, b1, acc);
        acc = MFMA32(a1f2, b2, acc);

        if (qv) {
            const int mq = (q >> 3) & 3;
            ushort_t* cellp = &a1s[q * 40 + 4 * g];
            #pragma unroll
            for (int qd = 0; qd < 4; ++qd) {
                float v0 = fmaxf(acc[qd * 4 + 0] + cb1[qd * 4 + 0], 0.f);
                float v1 = fmaxf(acc[qd * 4 + 1] + cb1[qd * 4 + 1], 0.f);
                float v2 = fmaxf(acc[qd * 4 + 2] + cb1[qd * 4 + 2], 0.f);
                float v3 = fmaxf(acc[qd * 4 + 3] + cb1[qd * 4 + 3], 0.f);
                uint2 pk;
                pk.x = inimg ? pk2bf(v0, v1) : 0u;
                pk.y = inimg ? pk2bf(v2, v3) : 0u;
                *(uint2*)&cellp[8 * (qd ^ mq)] = pk;
            }
        }
    }
    __syncthreads();

    // ---- conv2 via MFMA32, quad-mapped positions ----
    const int x2 = (n >> 2) * 2 + (n & 1);
    const int y2 = wave * 2 + ((n >> 1) & 1);

    short8 af[18];
    #pragma unroll
    for (int f = 0; f < 18; ++f)
        af[f] = *(const short8*)(w2f + (f * 64 + lane) * 8);

    f32x16 acc;
    #pragma unroll
    for (int i = 0; i < 16; ++i) acc[i] = 0.f;

    #pragma unroll
    for (int tau = 0; tau < 9; ++tau) {
        int dy = tau / 3, dx = tau % 3;
        int cell = (y2 + dy) * 18 + (x2 + dx);
        int mq = (cell >> 3) & 3;
        const ushort_t* bb = &a1s[cell * 40];
        int o0 = (g ^ mq) * 8;
        short8 b0 = *(const short8*)(bb + o0);
        short8 b1 = *(const short8*)(bb + (o0 ^ 16));
        acc = MFMA32(af[tau * 2 + 0], b0, acc);
        acc = MFMA32(af[tau * 2 + 1], b1, acc);
    }

    float pv[16];
    #pragma unroll
    for (int r = 0; r < 16; ++r) {
        float v = fmaxf(acc[r] + c2bs[(r & 3) + 8 * (r >> 2) + 4 * g], 0.f);
        v = dppadd<0xB1>(v);   // + x-neighbor (quad xor1)
        v = dppadd<0x4E>(v);   // + y-neighbor (quad xor2)
        pv[r] = v * 0.25f;
    }
    if ((n & 3) == 0) {
        const int poy = by * 8 + wave, pox = bx * 8 + (n >> 2);
        ushort_t* dst = &a2[(((size_t)b * 64 + poy) * 64 + pox) * 32 + 4 * g];
        #pragma unroll
        for (int qd = 0; qd < 4; ++qd) {
            uint2 pk;
            pk.x = pk2bf(pv[qd * 4 + 0], pv[qd * 4 + 1]);
            pk.y = pk2bf(pv[qd * 4 + 2], pv[qd * 4 + 3]);
            *(uint2*)&dst[8 * qd] = pk;
        }
    }
}

// ---------- K_B: conv3 (MFMA32, dual oc-tile, DPP pool) -> a3 bf16 NHWC [128][32][32][64]
__global__ __launch_bounds__(512, 4) void k_c3(
    const ushort_t* __restrict__ a2, const ushort_t* __restrict__ w3f,
    const float* __restrict__ c3b, ushort_t* __restrict__ a3)
{
    __shared__ __align__(16) ushort_t s[324 * 40];
    __shared__ float bs[64];
    const int t = threadIdx.x;
    const int bx = blockIdx.x, by = blockIdx.y, b = blockIdx.z;
    const int x0 = bx * 16, y0 = by * 16;
    if (t < 64) bs[t] = c3b[t];
    for (int idx = t; idx < 1296; idx += 512) {
        int cell = idx >> 2, part = idx & 3;
        int cy = cell / 18, cx = cell % 18;
        int gy = y0 - 1 + cy, gx = x0 - 1 + cx;
        uint4 v = make_uint4(0, 0, 0, 0);
        if (gy >= 0 && gy < 64 && gx >= 0 && gx < 64)
            v = *(const uint4*)(a2 + (((size_t)b * 64 + gy) * 64 + gx) * 32 + part * 8);
        int mq = (cell >> 3) & 3;
        *(uint4*)(&s[cell * 40 + (part ^ mq) * 8]) = v;
    }
    __syncthreads();

    const int wave = t >> 6, lane = t & 63;
    const int n = lane & 31, g = lane >> 5;
    const int x3 = (n >> 2) * 2 + (n & 1);
    const int y3 = wave * 2 + ((n >> 1) & 1);

    f32x16 acc0, acc1;
    #pragma unroll
    for (int i = 0; i < 16; ++i) { acc0[i] = 0.f; acc1[i] = 0.f; }

    #pragma unroll
    for (int tau = 0; tau < 9; ++tau) {
        int dy = tau / 3, dx = tau % 3;
        int cell = (y3 + dy) * 18 + (x3 + dx);
        int mq = (cell >> 3) & 3;
        const ushort_t* bb = &s[cell * 40];
        int o0 = (g ^ mq) * 8;
        short8 b0 = *(const short8*)(bb + o0);
        short8 b1 = *(const short8*)(bb + (o0 ^ 16));
        short8 a00 = *(const short8*)(w3f + ((tau * 2 + 0) * 64 + lane) * 8);
        short8 a01 = *(const short8*)(w3f + ((tau * 2 + 1) * 64 + lane) * 8);
        short8 a10 = *(const short8*)(w3f + (((18 + tau * 2) + 0) * 64 + lane) * 8);
        short8 a11 = *(const short8*)(w3f + (((18 + tau * 2) + 1) * 64 + lane) * 8);
        acc0 = MFMA32(a00, b0, acc0);
        acc0 = MFMA32(a01, b1, acc0);
        acc1 = MFMA32(a10, b0, acc1);
        acc1 = MFMA32(a11, b1, acc1);
    }

    const int poy = by * 8 + wave, pox = bx * 8 + (n >> 2);
    ushort_t* dst = &a3[(((size_t)b * 32 + poy) * 32 + pox) * 64 + 4 * g];
    #pragma unroll
    for (int ot = 0; ot < 2; ++ot) {
        const f32x16& ac = ot ? acc1 : acc0;
        float pv[16];
        #pragma unroll
        for (int r = 0; r < 16; ++r) {
            float v = fmaxf(ac[r] + bs[ot * 32 + (r & 3) + 8 * (r >> 2) + 4 * g], 0.f);
            v = dppadd<0xB1>(v);
            v = dppadd<0x4E>(v);
            pv[r] = v * 0.25f;
        }
        if ((n & 3) == 0) {
            #pragma unroll
            for (int qd = 0; qd < 4; ++qd) {
                uint2 pk;
                pk.x = pk2bf(pv[qd * 4 + 0], pv[qd * 4 + 1]);
                pk.y = pk2bf(pv[qd * 4 + 2], pv[qd * 4 + 3]);
                *(uint2*)&dst[ot * 32 + 8 * qd] = pk;
            }
        }
    }
}

// ---------- K_C: conv4 (MFMA32, dual oc-tile) + relu + global mean -> feat f32 [128][64]
__global__ __launch_bounds__(512, 2) void k_c4(
    const ushort_t* __restrict__ a3, const ushort_t* __restrict__ w4f,
    const float* __restrict__ c4b, float* __restrict__ feat)
{
    __shared__ __align__(16) ushort_t s[324 * 72];
    __shared__ float bs[64];
    const int t = threadIdx.x;
    const int bx = blockIdx.x, by = blockIdx.y, b = blockIdx.z;
    const int x0 = bx * 16, y0 = by * 16;
    if (t < 64) bs[t] = c4b[t];
    for (int idx = t; idx < 2592; idx += 512) {
        int cell = idx >> 3, part = idx & 7;
        int cy = cell / 18, cx = cell % 18;
        int gy = y0 - 1 + cy, gx = x0 - 1 + cx;
        uint4 v = make_uint4(0, 0, 0, 0);
        if (gy >= 0 && gy < 32 && gx >= 0 && gx < 32)
            v = *(const uint4*)(a3 + (((size_t)b * 32 + gy) * 32 + gx) * 64 + part * 8);
        int mq = (cell >> 3) & 3;
        *(uint4*)(&s[cell * 72 + (part ^ mq) * 8]) = v;
    }
    __syncthreads();

    const int wave = t >> 6, lane = t & 63;
    const int n = lane & 31, g = lane >> 5;
    const int ry = n >> 4, rx = n & 15;
    const int y4 = wave * 2 + ry;

    f32x16 acc0, acc1;
    #pragma unroll
    for (int i = 0; i < 16; ++i) { acc0[i] = 0.f; acc1[i] = 0.f; }

    #pragma unroll
    for (int hp = 0; hp < 2; ++hp) {
        #pragma unroll
        for (int tau = 0; tau < 9; ++tau) {
            int dy = tau / 3, dx = tau % 3;
            int cell = (y4 + dy) * 18 + (rx + dx);
            int mq = (cell >> 3) & 3;
            const ushort_t* bb = &s[cell * 72];
            int o0 = ((4 * hp + g) ^ mq) * 8;
            short8 b0 = *(const short8*)(bb + o0);
            short8 b1 = *(const short8*)(bb + (o0 ^ 16));
            short8 a00 = *(const short8*)(w4f + ((tau * 4 + hp * 2 + 0) * 64 + lane) * 8);
            short8 a01 = *(const short8*)(w4f + ((tau * 4 + hp * 2 + 1) * 64 + lane) * 8);
            short8 a10 = *(const short8*)(w4f + ((36 + tau * 4 + hp * 2 + 0) * 64 + lane) * 8);
            short8 a11 = *(const short8*)(w4f + ((36 + tau * 4 + hp * 2 + 1) * 64 + lane) * 8);
            acc0 = MFMA32(a00, b0, acc0);
            acc0 = MFMA32(a01, b1, acc0);
            acc1 = MFMA32(a10, b0, acc1);
            acc1 = MFMA32(a11, b1, acc1);
        }
    }

    #pragma unroll
    for (int ot = 0; ot < 2; ++ot) {
        const f32x16& ac = ot ? acc1 : acc0;
        #pragma unroll
        for (int r = 0; r < 16; ++r) {
            int oc = ot * 32 + (r & 3) + 8 * (r >> 2) + 4 * g;
            float v = fmaxf(ac[r] + bs[oc], 0.f);
            v = dppadd<0xB1>(v);   // xor1 (VALU)
            v = dppadd<0x4E>(v);   // xor2 (VALU)
            v += __shfl_xor(v, 4);
            v += __shfl_xor(v, 8);
            v += __shfl_xor(v, 16);
            if ((lane & 31) == 0)
                atomicAdd(&feat[b * 64 + oc], v * (1.0f / 1024.0f));
        }
    }
}

// ---------- router ----------
__global__ __launch_bounds__(256) void k_router(
    const float* __restrict__ meanacc,
    const float* __restrict__ pw, const float* __restrict__ pb,
    const float* __restrict__ rw, const float* __restrict__ rb,
    ushort_t* __restrict__ zb, int* __restrict__ top1, float* __restrict__ tail)
{
    __shared__ float m[64];
    __shared__ float zs[512];
    __shared__ float part[256];
    __shared__ float gate[16];
    const int b = blockIdx.x, t = threadIdx.x;
    if (t < 64) m[t] = meanacc[b * 64 + t];
    __syncthreads();

    #pragma unroll
    for (int j = 0; j < 2; ++j) {
        int d = t + j * 256;
        float s = pb[d];
        for (int c = 0; c < 64; ++c) s += m[c] * pw[c * 512 + d];
        zs[d] = s;
        zb[b * 512 + d] = f2bf(s);
    }
    __syncthreads();
    {
        int e = t & 15, gg = t >> 4;
        float s = 0.f;
        for (int j = 0; j < 32; ++j) {
            int d = gg * 32 + j;
            s += zs[d] * rw[d * 16 + e];
        }
        part[t] = s;
    }
    __syncthreads();
    if (t < 16) {
        float s = rb[t];
        for (int gg = 0; gg < 16; ++gg) s += part[gg * 16 + t];
        gate[t] = s;
    }
    __syncthreads();
    if (t == 0) {
        float mx = gate[0];
        int am = 0;
        for (int e = 1; e < 16; ++e)
            if (gate[e] > mx) { mx = gate[e]; am = e; }
        float pr[16];
        float sum = 0.f;
        for (int e = 0; e < 16; ++e) { pr[e] = expf(gate[e] - mx); sum += pr[e]; }
        float inv = 1.f / sum;
        top1[b] = am;
        atomicAdd(&tail[1 + am], 1.0f / 128.0f);
        for (int e = 0; e < 16; ++e)
            atomicAdd(&tail[17 + e], pr[e] * inv * (1.0f / 128.0f));
    }
}

// ---------- token sort + padded 32-row tile list + aux ----------
__global__ void k_sort(const int* __restrict__ top1, int* __restrict__ meta,
                       int* __restrict__ perm, float* __restrict__ tail)
{
    __shared__ int c[16], o[16], pos[128];
    const int t = threadIdx.x;
    if (t < 16) c[t] = 0;
    __syncthreads();
    int e = 0;
    if (t < 128) { e = top1[t]; pos[t] = atomicAdd(&c[e], 1); }
    __syncthreads();
    if (t == 0) {
        int s = 0;
        for (int i = 0; i < 16; ++i) { o[i] = s; s += c[i]; }
        int nt = 0;
        for (int i = 0; i < 16; ++i) {
            for (int r0 = 0; r0 < c[i]; r0 += 32) {
                meta[33 + nt] = i;
                meta[53 + nt] = o[i] + r0;
                int rem = c[i] - r0;
                meta[73 + nt] = rem < 32 ? rem : 32;
                ++nt;
            }
        }
        meta[32] = nt;
        for (int k = nt; k < 20; ++k) { meta[33 + k] = 0; meta[53 + k] = 0; meta[73 + k] = 0; }
        float s2 = 0.f;
        for (int i = 0; i < 16; ++i) s2 += tail[1 + i] * tail[17 + i];
        tail[0] = 16.0f * s2;
    }
    __syncthreads();
    if (t < 128) perm[o[e] + pos[t]] = t;
    if (t < 16) { meta[t] = c[t]; meta[16 + t] = o[t]; }
}

// ---------- expert layer 1: h1 = relu(z @ w1[e] + b1) ----------
__global__ __launch_bounds__(64) void k_mlp1(
    const ushort_t* __restrict__ zb, const int* __restrict__ meta, const int* __restrict__ perm,
    const float* __restrict__ w1, const float* __restrict__ b1, ushort_t* __restrict__ h1b)
{
    const int ty = blockIdx.y;
    if (ty >= meta[32]) return;
    const int e = meta[33 + ty], ts = meta[53 + ty], rows = meta[73 + ty];
    const int n0 = blockIdx.x * 32;
    __shared__ __align__(16) ushort_t ws[32 * 520];
    __shared__ int tks[32];
    const int lane = threadIdx.x;
    const int mn = lane & 31, g = lane >> 5;

    if (lane < 32) tks[lane] = (lane < rows) ? perm[ts + lane] : -1;

    const float* Wg = w1 + ((size_t)e << 18) + n0;
    {
        const int cq = lane & 7, dg = lane >> 3;
        #pragma unroll 4
        for (int it = 0; it < 32; ++it) {
            int d = it * 16 + dg * 2;
            float4 va = *(const float4*)(Wg + (size_t)d * 512 + 4 * cq);
            float4 vb = *(const float4*)(Wg + (size_t)(d + 1) * 512 + 4 * cq);
            *(unsigned*)&ws[(4 * cq + 0) * 520 + d] = pk2bf(va.x, vb.x);
            *(unsigned*)&ws[(4 * cq + 1) * 520 + d] = pk2bf(va.y, vb.y);
            *(unsigned*)&ws[(4 * cq + 2) * 520 + d] = pk2bf(va.z, vb.z);
            *(unsigned*)&ws[(4 * cq + 3) * 520 + d] = pk2bf(va.w, vb.w);
        }
    }
    __syncthreads();

    const int tok_a = tks[mn] < 0 ? 0 : tks[mn];
    const ushort_t* za = zb + (size_t)tok_a * 512;

    f32x16 acc;
    #pragma unroll
    for (int i = 0; i < 16; ++i) acc[i] = 0.f;

    #pragma unroll 4
    for (int kt = 0; kt < 16; ++kt) {
        int k0 = kt * 32;
        short8 a0 = *(const short8*)(za + k0 + g * 8);
        short8 a1 = *(const short8*)(za + k0 + 16 + g * 8);
        short8 b0 = *(const short8*)(&ws[mn * 520 + k0 + g * 8]);
        short8 b1 = *(const short8*)(&ws[mn * 520 + k0 + 16 + g * 8]);
        acc = MFMA32(a0, b0, acc);
        acc = MFMA32(a1, b1, acc);
    }

    const float bias = b1[e * 512 + n0 + mn];
    #pragma unroll
    for (int r = 0; r < 16; ++r) {
        int mrow = (r & 3) + 8 * (r >> 2) + 4 * g;
        int tok = tks[mrow];
        if (tok >= 0) {
            float v = fmaxf(acc[r] + bias, 0.f);
            h1b[(size_t)tok * 512 + n0 + mn] = f2bf(v);
        }
    }
}

// ---------- expert layer 2: out = h1 @ w2[e] + b2 ----------
__global__ __launch_bounds__(64) void k_mlp2(
    const ushort_t* __restrict__ h1b, const int* __restrict__ meta, const int* __restrict__ perm,
    const float* __restrict__ w2, const float* __restrict__ b2, float* __restrict__ out)
{
    const int ty = blockIdx.y;
    if (ty >= meta[32]) return;
    const int e = meta[33 + ty], ts = meta[53 + ty], rows = meta[73 + ty];
    const int n0 = blockIdx.x * 32;
    __shared__ __align__(16) ushort_t ws[32 * 520];
    __shared__ int tks[32];
    const int lane = threadIdx.x;
    const int mn = lane & 31, g = lane >> 5;

    if (lane < 32) tks[lane] = (lane < rows) ? perm[ts + lane] : -1;

    const float* Wg = w2 + (size_t)e * 512000 + n0;
    {
        const int cq = lane & 7, dg = lane >> 3;
        const bool cut = (n0 == 992) && (cq >= 2);
        #pragma unroll 4
        for (int it = 0; it < 32; ++it) {
            int d = it * 16 + dg * 2;
            float4 va = make_float4(0.f, 0.f, 0.f, 0.f), vb = va;
            if (!cut) {
                va = *(const float4*)(Wg + (size_t)d * 1000 + 4 * cq);
                vb = *(const float4*)(Wg + (size_t)(d + 1) * 1000 + 4 * cq);
            }
            *(unsigned*)&ws[(4 * cq + 0) * 520 + d] = pk2bf(va.x, vb.x);
            *(unsigned*)&ws[(4 * cq + 1) * 520 + d] = pk2bf(va.y, vb.y);
            *(unsigned*)&ws[(4 * cq + 2) * 520 + d] = pk2bf(va.z, vb.z);
            *(unsigned*)&ws[(4 * cq + 3) * 520 + d] = pk2bf(va.w, vb.w);
        }
    }
    __syncthreads();

    const int tok_a = tks[mn] < 0 ? 0 : tks[mn];
    const ushort_t* ha = h1b + (size_t)tok_a * 512;

    f32x16 acc;
    #pragma unroll
    for (int i = 0; i < 16; ++i) acc[i] = 0.f;

    #pragma unroll 4
    for (int kt = 0; kt < 16; ++kt) {
        int k0 = kt * 32;
        short8 a0 = *(const short8*)(ha + k0 + g * 8);
        short8 a1 = *(const short8*)(ha + k0 + 16 + g * 8);
        short8 b0 = *(const short8*)(&ws[mn * 520 + k0 + g * 8]);
        short8 b1 = *(const short8*)(&ws[mn * 520 + k0 + 16 + g * 8]);
        acc = MFMA32(a0, b0, acc);
        acc = MFMA32(a1, b1, acc);
    }

    const int col = n0 + mn;
    if (col < 1000) {
        const float bias = b2[e * 1000 + col];
        #pragma unroll
        for (int r = 0; r < 16; ++r) {
            int mrow = (r & 3) + 8 * (r >> 2) + 4 * g;
            int tok = tks[mrow];
            if (tok >= 0)
                out[(size_t)tok * 1000 + col] = acc[r] + bias;
        }
    }
}

extern "C" void kernel_launch(void* const* d_in, const int* in_sizes, int n_in,
                              void* d_out, int out_size, void* d_ws, size_t ws_size,
                              hipStream_t stream)
{
    const float* x   = (const float*)d_in[0];
    const float* c1w = (const float*)d_in[1];
    const float* c1b = (const float*)d_in[2];
    const float* c2w = (const float*)d_in[3];
    const float* c2b = (const float*)d_in[4];
    const float* c3w = (const float*)d_in[5];
    const float* c3b = (const float*)d_in[6];
    const float* c4w = (const float*)d_in[7];
    const float* c4b = (const float*)d_in[8];
    const float* pw  = (const float*)d_in[9];
    const float* pb  = (const float*)d_in[10];
    const float* rw  = (const float*)d_in[11];
    const float* rb  = (const float*)d_in[12];
    const float* w1  = (const float*)d_in[13];
    const float* b1  = (const float*)d_in[14];
    const float* w2  = (const float*)d_in[15];
    const float* b2  = (const float*)d_in[16];

    float* out = (float*)d_out;
    float* tail = out + 128000;   // aux, counts[16], importance[16]

    char* w = (char*)d_ws;
    ushort_t* a2   = (ushort_t*)(w);                  // 33554432 B
    ushort_t* a3   = (ushort_t*)(w + 33554432);       // 16777216 B
    ushort_t* w2f  = (ushort_t*)(w + 50331648);       // 18432 B
    ushort_t* w3f  = (ushort_t*)(w + 50350080);       // 36864 B
    ushort_t* w4f  = (ushort_t*)(w + 50386944);       // 73728 B
    ushort_t* c1f  = (ushort_t*)(w + 50460672);       // 3072 B
    float*    feat = (float*)(w + 50464768);          // 32768 B
    ushort_t* zb   = (ushort_t*)(w + 50497536);       // 131072 B
    ushort_t* h1b  = (ushort_t*)(w + 50628608);       // 131072 B
    int*      top1 = (int*)(w + 50759680);            // 512 B
    int*      meta = (int*)(w + 50760192);            // 512 B
    int*      perm = (int*)(w + 50760704);            // 512 B

    k_wcvt  <<<34, 256, 0, stream>>>(c1w, c2w, c3w, c4w, c1f, w2f, w3f, w4f, feat, tail);
    k_c12   <<<dim3(8, 8, 128), 512, 0, stream>>>(x, c1f, c1b, w2f, c2b, a2);
    k_c3    <<<dim3(4, 4, 128), 512, 0, stream>>>(a2, w3f, c3b, a3);
    k_c4    <<<dim3(2, 2, 128), 512, 0, stream>>>(a3, w4f, c4b, feat);
    k_router<<<128, 256, 0, stream>>>(feat, pw, pb, rw, rb, zb, top1, tail);
    k_sort  <<<1, 128, 0, stream>>>(top1, meta, perm, tail);
    k_mlp1  <<<dim3(16, 20), 64, 0, stream>>>(zb, meta, perm, w1, b1, h1b);
    k_mlp2  <<<dim3(32, 20), 64, 0, stream>>>(h1b, meta, perm, w2, b2, out);
}

// Round 12
// 192.805 us; speedup vs baseline: 1.1016x; 1.0061x over previous
//
#include <hip/hip_runtime.h>
#include <math.h>

typedef unsigned short ushort_t;
typedef short short4x __attribute__((ext_vector_type(4)));
typedef short short8 __attribute__((ext_vector_type(8)));
typedef float f32x16 __attribute__((ext_vector_type(16)));

#define MFMA32(A,B,C) __builtin_amdgcn_mfma_f32_32x32x16_bf16(A,B,C,0,0,0)

__device__ __forceinline__ ushort_t f2bf(float f) {
    union { float f; unsigned u; } c; c.f = f;
    unsigned u = c.u;
    unsigned r = (u + 0x7FFFu + ((u >> 16) & 1u)) >> 16;
    return (ushort_t)r;
}

__device__ __forceinline__ unsigned pk2bf(float lo, float hi) {
    unsigned r;
    asm("v_cvt_pk_bf16_f32 %0, %1, %2" : "=v"(r) : "v"(lo), "v"(hi));
    return r;
}

// v + quad_perm(v): cross-lane add on the VALU pipe
// 0xB1 = [1,0,3,2] (xor1), 0x4E = [2,3,0,1] (xor2)
template<int CTRL>
__device__ __forceinline__ float dppadd(float v) {
    int p = __builtin_amdgcn_mov_dpp(__builtin_bit_cast(int, v), CTRL, 0xF, 0xF, true);
    return v + __builtin_bit_cast(float, p);
}

// ---------- weight repack + output-scalar zeroing ----------
// conv2/3/4: kappa(g,j) = g*8+j per K=16 slice. Pool/mean scales folded into weights:
// w2f,w3f *= 0.25 ; w4f *= 1/1024. conv1: k = pixel*4 + channel; k==3 slot carries c1b.
__global__ __launch_bounds__(256) void k_wcvt(
    const float* __restrict__ c1w, const float* __restrict__ c1b_,
    const float* __restrict__ c2w, const float* __restrict__ c3w, const float* __restrict__ c4w,
    ushort_t* __restrict__ c1f, ushort_t* __restrict__ w2f,
    ushort_t* __restrict__ w3f, ushort_t* __restrict__ w4f,
    float* __restrict__ feat, float* __restrict__ tail)
{
    if (blockIdx.x == 33) {
        for (int i = threadIdx.x; i < 8192; i += 256) feat[i] = 0.f;
        if (threadIdx.x < 33) tail[threadIdx.x] = 0.f;
        return;
    }
    int r = blockIdx.x * 256 + threadIdx.x;
    int lane = r & 63, m = lane & 31, g = (lane >> 5) & 1;
    if (r < 1152) {                       // conv2: f = tau*2+h  (x0.25)
        int f = r >> 6, tau = f >> 1, h = f & 1, ky = tau / 3, kx = tau % 3;
        #pragma unroll
        for (int j = 0; j < 8; ++j) {
            int ic = h * 16 + g * 8 + j;
            w2f[r * 8 + j] = f2bf(0.25f * c2w[((m * 32 + ic) * 3 + ky) * 3 + kx]);
        }
    } else if (r < 3456) {                // conv3: f = ot*18 + tau*2 + h  (x0.25)
        int rr = r - 1152;
        int f = rr >> 6;
        int ot = f / 18, fl = f % 18, tau = fl >> 1, h = fl & 1, ky = tau / 3, kx = tau % 3;
        int oc = ot * 32 + m;
        #pragma unroll
        for (int j = 0; j < 8; ++j) {
            int ic = h * 16 + g * 8 + j;
            w3f[rr * 8 + j] = f2bf(0.25f * c3w[((oc * 32 + ic) * 3 + ky) * 3 + kx]);
        }
    } else if (r < 8064) {                // conv4: f = ot*36 + tau*4 + h  (x 1/1024)
        int rr = r - 3456;
        int f = rr >> 6;
        int ot = f / 36, fl = f % 36, tau = fl >> 2, h = fl & 3, ky = tau / 3, kx = tau % 3;
        int oc = ot * 32 + m;
        #pragma unroll
        for (int j = 0; j < 8; ++j) {
            int ic = h * 16 + g * 8 + j;
            w4f[rr * 8 + j] = f2bf(0.0009765625f * c4w[((oc * 64 + ic) * 3 + ky) * 3 + kx]);
        }
    } else if (r < 8256) {                // conv1: 3 frags, k = p*4 + c (K=48); k==3 = bias
        int rr = r - 8064;
        int f1 = rr >> 6;
        #pragma unroll
        for (int j = 0; j < 8; ++j) {
            int k = f1 * 16 + g * 8 + j;
            int p = k >> 2, c = k & 3;
            ushort_t v = 0;
            if (p < 9 && c < 3)
                v = f2bf(c1w[(m * 3 + c) * 9 + p]);
            else if (k == 3)
                v = f2bf(c1b_[m]);
            c1f[rr * 8 + j] = v;
        }
    }
}

// ---------- K_A: conv1 (MFMA32, bias-in-MFMA) + conv2 (MFMA32, DPP pool) -> a2 [128][64][64][32]
__global__ __launch_bounds__(512, 4) void k_c12(
    const float* __restrict__ x,
    const ushort_t* __restrict__ c1f,
    const ushort_t* __restrict__ w2f, const float* __restrict__ c2b,
    ushort_t* __restrict__ a2)
{
    __shared__ __align__(16) ushort_t xs[1600];        // [20][20][4]; ch3 = 1.0 (bias lane)
    __shared__ __align__(16) ushort_t a1s[324 * 40];   // 18x18 cells, 32 ic + 8 pad (linear)
    __shared__ float c2bs[32];
    const int t = threadIdx.x;
    const int bx = blockIdx.x, by = blockIdx.y, b = blockIdx.z;
    const int ox0 = bx * 16, oy0 = by * 16;

    if (t < 32) c2bs[t] = 0.25f * c2b[t];
    for (int i = t; i < 400; i += 512) {
        int yy = i / 20, xx = i % 20;
        int gy = oy0 - 2 + yy, gx = ox0 - 2 + xx;
        float v0 = 0.f, v1 = 0.f, v2 = 0.f;
        if (gy >= 0 && gy < 128 && gx >= 0 && gx < 128) {
            const float* px = x + ((size_t)(b * 3) * 128 + gy) * 128 + gx;
            v0 = px[0]; v1 = px[16384]; v2 = px[32768];
        }
        uint2 pk;
        pk.x = pk2bf(v0, v1);
        pk.y = pk2bf(v2, 1.0f);          // ch3 = 1.0 -> MFMA adds bias via k==3 weight
        *(uint2*)&xs[i * 4] = pk;
    }

    const int wave = t >> 6, lane = t & 63;
    const int n = lane & 31, g = lane >> 5;

    short8 a1f0 = *(const short8*)(c1f + lane * 8);
    short8 a1f1 = *(const short8*)(c1f + (64 + lane) * 8);
    short8 a1f2 = *(const short8*)(c1f + (128 + lane) * 8);
    __syncthreads();

    // ---- conv1 via MFMA32 over 11 groups of 32 halo cells (324) ----
    for (int grp = wave; grp < 11; grp += 8) {
        int q = grp * 32 + n;
        bool qv = q < 324;
        int qc = qv ? q : 0;
        int cy = qc / 18, cx = qc % 18;
        int gy = oy0 - 1 + cy, gx = ox0 - 1 + cx;
        bool inimg = qv && gy >= 0 && gy < 128 && gx >= 0 && gx < 128;
        int base = (cy * 20 + cx) * 4;

        short4x q0 = *(const short4x*)&xs[base + (g ? 8 : 0)];
        short4x q1 = *(const short4x*)&xs[base + (g ? 80 : 4)];
        short4x q2 = *(const short4x*)&xs[base + (g ? 160 : 84)];
        short4x q3 = *(const short4x*)&xs[base + (g ? 164 : 88)];
        short4x q4 = *(const short4x*)&xs[base + 168];

        short8 b0 = __builtin_shufflevector(q0, q1, 0, 1, 2, 3, 4, 5, 6, 7);
        short8 b1 = __builtin_shufflevector(q2, q3, 0, 1, 2, 3, 4, 5, 6, 7);
        short8 b2 = __builtin_shufflevector(q4, q4, 0, 1, 2, 3, 0, 1, 2, 3);

        f32x16 acc;
        #pragma unroll
        for (int i = 0; i < 16; ++i) acc[i] = 0.f;
        acc = MFMA32(a1f0, b0, acc);
        acc = MFMA32(a1f1, b1, acc);
        acc = MFMA32(a1f2, b2, acc);

        if (qv) {
            ushort_t* dst = &a1s[q * 40 + 4 * g];
            #pragma unroll
            for (int qd = 0; qd < 4; ++qd) {
                float v0 = fmaxf(acc[qd * 4 + 0], 0.f);
                float v1 = fmaxf(acc[qd * 4 + 1], 0.f);
                float v2 = fmaxf(acc[qd * 4 + 2], 0.f);
                float v3 = fmaxf(acc[qd * 4 + 3], 0.f);
                uint2 pk;
                pk.x = inimg ? pk2bf(v0, v1) : 0u;
                pk.y = inimg ? pk2bf(v2, v3) : 0u;
                *(uint2*)&dst[8 * qd] = pk;
            }
        }
    }
    __syncthreads();

    // ---- conv2 via MFMA32, quad-mapped positions, immediate-offset LDS reads ----
    const int x2 = (n >> 2) * 2 + (n & 1);
    const int y2 = wave * 2 + ((n >> 1) & 1);

    short8 af[18];
    #pragma unroll
    for (int f = 0; f < 18; ++f)
        af[f] = *(const short8*)(w2f + (f * 64 + lane) * 8);

    f32x16 acc;
    #pragma unroll
    for (int i = 0; i < 16; ++i) acc[i] = 0.f;

    const ushort_t* bbase = &a1s[(y2 * 18 + x2) * 40 + g * 8];
    #pragma unroll
    for (int tau = 0; tau < 9; ++tau) {
        const int off = ((tau / 3) * 18 + (tau % 3)) * 40;
        short8 b0 = *(const short8*)(bbase + off);
        short8 b1 = *(const short8*)(bbase + off + 16);
        acc = MFMA32(af[tau * 2 + 0], b0, acc);
        acc = MFMA32(af[tau * 2 + 1], b1, acc);
    }

    float pv[16];
    #pragma unroll
    for (int r = 0; r < 16; ++r) {
        float v = fmaxf(acc[r] + c2bs[(r & 3) + 8 * (r >> 2) + 4 * g], 0.f);
        v = dppadd<0xB1>(v);
        v = dppadd<0x4E>(v);
        pv[r] = v;
    }
    if ((n & 3) == 0) {
        const int poy = by * 8 + wave, pox = bx * 8 + (n >> 2);
        ushort_t* dst = &a2[(((size_t)b * 64 + poy) * 64 + pox) * 32 + 4 * g];
        #pragma unroll
        for (int qd = 0; qd < 4; ++qd) {
            uint2 pk;
            pk.x = pk2bf(pv[qd * 4 + 0], pv[qd * 4 + 1]);
            pk.y = pk2bf(pv[qd * 4 + 2], pv[qd * 4 + 3]);
            *(uint2*)&dst[8 * qd] = pk;
        }
    }
}

// ---------- K_B: conv3 (MFMA32, dual oc-tile, DPP pool) -> a3 [128][32][32][64]
__global__ __launch_bounds__(512, 4) void k_c3(
    const ushort_t* __restrict__ a2, const ushort_t* __restrict__ w3f,
    const float* __restrict__ c3b, ushort_t* __restrict__ a3)
{
    __shared__ __align__(16) ushort_t s[324 * 40];
    __shared__ float bs[64];
    const int t = threadIdx.x;
    const int bx = blockIdx.x, by = blockIdx.y, b = blockIdx.z;
    const int x0 = bx * 16, y0 = by * 16;
    if (t < 64) bs[t] = 0.25f * c3b[t];
    for (int idx = t; idx < 1296; idx += 512) {
        int cell = idx >> 2, part = idx & 3;
        int cy = cell / 18, cx = cell % 18;
        int gy = y0 - 1 + cy, gx = x0 - 1 + cx;
        uint4 v = make_uint4(0, 0, 0, 0);
        if (gy >= 0 && gy < 64 && gx >= 0 && gx < 64)
            v = *(const uint4*)(a2 + (((size_t)b * 64 + gy) * 64 + gx) * 32 + part * 8);
        *(uint4*)(&s[cell * 40 + part * 8]) = v;
    }
    __syncthreads();

    const int wave = t >> 6, lane = t & 63;
    const int n = lane & 31, g = lane >> 5;
    const int x3 = (n >> 2) * 2 + (n & 1);
    const int y3 = wave * 2 + ((n >> 1) & 1);

    f32x16 acc0, acc1;
    #pragma unroll
    for (int i = 0; i < 16; ++i) { acc0[i] = 0.f; acc1[i] = 0.f; }

    const ushort_t* bbase = &s[(y3 * 18 + x3) * 40 + g * 8];
    #pragma unroll
    for (int tau = 0; tau < 9; ++tau) {
        const int off = ((tau / 3) * 18 + (tau % 3)) * 40;
        short8 b0 = *(const short8*)(bbase + off);
        short8 b1 = *(const short8*)(bbase + off + 16);
        short8 a00 = *(const short8*)(w3f + ((tau * 2 + 0) * 64 + lane) * 8);
        short8 a01 = *(const short8*)(w3f + ((tau * 2 + 1) * 64 + lane) * 8);
        short8 a10 = *(const short8*)(w3f + (((18 + tau * 2) + 0) * 64 + lane) * 8);
        short8 a11 = *(const short8*)(w3f + (((18 + tau * 2) + 1) * 64 + lane) * 8);
        acc0 = MFMA32(a00, b0, acc0);
        acc0 = MFMA32(a01, b1, acc0);
        acc1 = MFMA32(a10, b0, acc1);
        acc1 = MFMA32(a11, b1, acc1);
    }

    const int poy = by * 8 + wave, pox = bx * 8 + (n >> 2);
    ushort_t* dst = &a3[(((size_t)b * 32 + poy) * 32 + pox) * 64 + 4 * g];
    #pragma unroll
    for (int ot = 0; ot < 2; ++ot) {
        const f32x16& ac = ot ? acc1 : acc0;
        float pv[16];
        #pragma unroll
        for (int r = 0; r < 16; ++r) {
            float v = fmaxf(ac[r] + bs[ot * 32 + (r & 3) + 8 * (r >> 2) + 4 * g], 0.f);
            v = dppadd<0xB1>(v);
            v = dppadd<0x4E>(v);
            pv[r] = v;
        }
        if ((n & 3) == 0) {
            #pragma unroll
            for (int qd = 0; qd < 4; ++qd) {
                uint2 pk;
                pk.x = pk2bf(pv[qd * 4 + 0], pv[qd * 4 + 1]);
                pk.y = pk2bf(pv[qd * 4 + 2], pv[qd * 4 + 3]);
                *(uint2*)&dst[ot * 32 + 8 * qd] = pk;
            }
        }
    }
}

// ---------- K_C: conv4 (MFMA32, dual oc-tile) + relu + global mean -> feat f32 [128][64]
__global__ __launch_bounds__(512, 2) void k_c4(
    const ushort_t* __restrict__ a3, const ushort_t* __restrict__ w4f,
    const float* __restrict__ c4b, float* __restrict__ feat)
{
    __shared__ __align__(16) ushort_t s[324 * 72];
    __shared__ float bs[64];
    const int t = threadIdx.x;
    const int bx = blockIdx.x, by = blockIdx.y, b = blockIdx.z;
    const int x0 = bx * 16, y0 = by * 16;
    if (t < 64) bs[t] = 0.0009765625f * c4b[t];
    for (int idx = t; idx < 2592; idx += 512) {
        int cell = idx >> 3, part = idx & 7;
        int cy = cell / 18, cx = cell % 18;
        int gy = y0 - 1 + cy, gx = x0 - 1 + cx;
        uint4 v = make_uint4(0, 0, 0, 0);
        if (gy >= 0 && gy < 32 && gx >= 0 && gx < 32)
            v = *(const uint4*)(a3 + (((size_t)b * 32 + gy) * 32 + gx) * 64 + part * 8);
        *(uint4*)(&s[cell * 72 + part * 8]) = v;
    }
    __syncthreads();

    const int wave = t >> 6, lane = t & 63;
    const int n = lane & 31, g = lane >> 5;
    const int ry = n >> 4, rx = n & 15;
    const int y4 = wave * 2 + ry;

    f32x16 acc0, acc1;
    #pragma unroll
    for (int i = 0; i < 16; ++i) { acc0[i] = 0.f; acc1[i] = 0.f; }

    const ushort_t* bbase = &s[(y4 * 18 + rx) * 72 + g * 8];
    #pragma unroll
    for (int hp = 0; hp < 2; ++hp) {
        #pragma unroll
        for (int tau = 0; tau < 9; ++tau) {
            const int off = ((tau / 3) * 18 + (tau % 3)) * 72 + hp * 32;
            short8 b0 = *(const short8*)(bbase + off);
            short8 b1 = *(const short8*)(bbase + off + 16);
            short8 a00 = *(const short8*)(w4f + ((tau * 4 + hp * 2 + 0) * 64 + lane) * 8);
            short8 a01 = *(const short8*)(w4f + ((tau * 4 + hp * 2 + 1) * 64 + lane) * 8);
            short8 a10 = *(const short8*)(w4f + ((36 + tau * 4 + hp * 2 + 0) * 64 + lane) * 8);
            short8 a11 = *(const short8*)(w4f + ((36 + tau * 4 + hp * 2 + 1) * 64 + lane) * 8);
            acc0 = MFMA32(a00, b0, acc0);
            acc0 = MFMA32(a01, b1, acc0);
            acc1 = MFMA32(a10, b0, acc1);
            acc1 = MFMA32(a11, b1, acc1);
        }
    }

    #pragma unroll
    for (int ot = 0; ot < 2; ++ot) {
        const f32x16& ac = ot ? acc1 : acc0;
        #pragma unroll
        for (int r = 0; r < 16; ++r) {
            int oc = ot * 32 + (r & 3) + 8 * (r >> 2) + 4 * g;
            float v = fmaxf(ac[r] + bs[oc], 0.f);
            v = dppadd<0xB1>(v);
            v = dppadd<0x4E>(v);
            v += __shfl_xor(v, 4);
            v += __shfl_xor(v, 8);
            v += __shfl_xor(v, 16);
            if ((lane & 31) == 0)
                atomicAdd(&feat[b * 64 + oc], v);
        }
    }
}

// ---------- router ----------
__global__ __launch_bounds__(256) void k_router(
    const float* __restrict__ meanacc,
    const float* __restrict__ pw, const float* __restrict__ pb,
    const float* __restrict__ rw, const float* __restrict__ rb,
    ushort_t* __restrict__ zb, int* __restrict__ top1, float* __restrict__ tail)
{
    __shared__ float m[64];
    __shared__ float zs[512];
    __shared__ float part[256];
    __shared__ float gate[16];
    const int b = blockIdx.x, t = threadIdx.x;
    if (t < 64) m[t] = meanacc[b * 64 + t];
    __syncthreads();

    #pragma unroll
    for (int j = 0; j < 2; ++j) {
        int d = t + j * 256;
        float s = pb[d];
        for (int c = 0; c < 64; ++c) s += m[c] * pw[c * 512 + d];
        zs[d] = s;
        zb[b * 512 + d] = f2bf(s);
    }
    __syncthreads();
    {
        int e = t & 15, gg = t >> 4;
        float s = 0.f;
        for (int j = 0; j < 32; ++j) {
            int d = gg * 32 + j;
            s += zs[d] * rw[d * 16 + e];
        }
        part[t] = s;
    }
    __syncthreads();
    if (t < 16) {
        float s = rb[t];
        for (int gg = 0; gg < 16; ++gg) s += part[gg * 16 + t];
        gate[t] = s;
    }
    __syncthreads();
    if (t == 0) {
        float mx = gate[0];
        int am = 0;
        for (int e = 1; e < 16; ++e)
            if (gate[e] > mx) { mx = gate[e]; am = e; }
        float pr[16];
        float sum = 0.f;
        for (int e = 0; e < 16; ++e) { pr[e] = expf(gate[e] - mx); sum += pr[e]; }
        float inv = 1.f / sum;
        top1[b] = am;
        atomicAdd(&tail[1 + am], 1.0f / 128.0f);
        for (int e = 0; e < 16; ++e)
            atomicAdd(&tail[17 + e], pr[e] * inv * (1.0f / 128.0f));
    }
}

// ---------- token sort + padded 32-row tile list + aux ----------
__global__ void k_sort(const int* __restrict__ top1, int* __restrict__ meta,
                       int* __restrict__ perm, float* __restrict__ tail)
{
    __shared__ int c[16], o[16], pos[128];
    const int t = threadIdx.x;
    if (t < 16) c[t] = 0;
    __syncthreads();
    int e = 0;
    if (t < 128) { e = top1[t]; pos[t] = atomicAdd(&c[e], 1); }
    __syncthreads();
    if (t == 0) {
        int s = 0;
        for (int i = 0; i < 16; ++i) { o[i] = s; s += c[i]; }
        int nt = 0;
        for (int i = 0; i < 16; ++i) {
            for (int r0 = 0; r0 < c[i]; r0 += 32) {
                meta[33 + nt] = i;
                meta[53 + nt] = o[i] + r0;
                int rem = c[i] - r0;
                meta[73 + nt] = rem < 32 ? rem : 32;
                ++nt;
            }
        }
        meta[32] = nt;
        for (int k = nt; k < 20; ++k) { meta[33 + k] = 0; meta[53 + k] = 0; meta[73 + k] = 0; }
        float s2 = 0.f;
        for (int i = 0; i < 16; ++i) s2 += tail[1 + i] * tail[17 + i];
        tail[0] = 16.0f * s2;
    }
    __syncthreads();
    if (t < 128) perm[o[e] + pos[t]] = t;
    if (t < 16) { meta[t] = c[t]; meta[16 + t] = o[t]; }
}

// ---------- expert layer 1: h1 = relu(z @ w1[e] + b1) ----------
__global__ __launch_bounds__(64) void k_mlp1(
    const ushort_t* __restrict__ zb, const int* __restrict__ meta, const int* __restrict__ perm,
    const float* __restrict__ w1, const float* __restrict__ b1, ushort_t* __restrict__ h1b)
{
    const int ty = blockIdx.y;
    if (ty >= meta[32]) return;
    const int e = meta[33 + ty], ts = meta[53 + ty], rows = meta[73 + ty];
    const int n0 = blockIdx.x * 32;
    __shared__ __align__(16) ushort_t ws[32 * 520];
    __shared__ int tks[32];
    const int lane = threadIdx.x;
    const int mn = lane & 31, g = lane >> 5;

    if (lane < 32) tks[lane] = (lane < rows) ? perm[ts + lane] : -1;

    const float* Wg = w1 + ((size_t)e << 18) + n0;
    {
        const int cq = lane & 7, dg = lane >> 3;
        #pragma unroll 4
        for (int it = 0; it < 32; ++it) {
            int d = it * 16 + dg * 2;
            float4 va = *(const float4*)(Wg + (size_t)d * 512 + 4 * cq);
            float4 vb = *(const float4*)(Wg + (size_t)(d + 1) * 512 + 4 * cq);
            *(unsigned*)&ws[(4 * cq + 0) * 520 + d] = pk2bf(va.x, vb.x);
            *(unsigned*)&ws[(4 * cq + 1) * 520 + d] = pk2bf(va.y, vb.y);
            *(unsigned*)&ws[(4 * cq + 2) * 520 + d] = pk2bf(va.z, vb.z);
            *(unsigned*)&ws[(4 * cq + 3) * 520 + d] = pk2bf(va.w, vb.w);
        }
    }
    __syncthreads();

    const int tok_a = tks[mn] < 0 ? 0 : tks[mn];
    const ushort_t* za = zb + (size_t)tok_a * 512;

    f32x16 acc;
    #pragma unroll
    for (int i = 0; i < 16; ++i) acc[i] = 0.f;

    #pragma unroll 4
    for (int kt = 0; kt < 16; ++kt) {
        int k0 = kt * 32;
        short8 a0 = *(const short8*)(za + k0 + g * 8);
        short8 a1 = *(const short8*)(za + k0 + 16 + g * 8);
        short8 b0 = *(const short8*)(&ws[mn * 520 + k0 + g * 8]);
        short8 b1 = *(const short8*)(&ws[mn * 520 + k0 + 16 + g * 8]);
        acc = MFMA32(a0, b0, acc);
        acc = MFMA32(a1, b1, acc);
    }

    const float bias = b1[e * 512 + n0 + mn];
    #pragma unroll
    for (int r = 0; r < 16; ++r) {
        int mrow = (r & 3) + 8 * (r >> 2) + 4 * g;
        int tok = tks[mrow];
        if (tok >= 0) {
            float v = fmaxf(acc[r] + bias, 0.f);
            h1b[(size_t)tok * 512 + n0 + mn] = f2bf(v);
        }
    }
}

// ---------- expert layer 2: out = h1 @ w2[e] + b2 ----------
__global__ __launch_bounds__(64) void k_mlp2(
    const ushort_t* __restrict__ h1b, const int* __restrict__ meta, const int* __restrict__ perm,
    const float* __restrict__ w2, const float* __restrict__ b2, float* __restrict__ out)
{
    const int ty = blockIdx.y;
    if (ty >= meta[32]) return;
    const int e = meta[33 + ty], ts = meta[53 + ty], rows = meta[73 + ty];
    const int n0 = blockIdx.x * 32;
    __shared__ __align__(16) ushort_t ws[32 * 520];
    __shared__ int tks[32];
    const int lane = threadIdx.x;
    const int mn = lane & 31, g = lane >> 5;

    if (lane < 32) tks[lane] = (lane < rows) ? perm[ts + lane] : -1;

    const float* Wg = w2 + (size_t)e * 512000 + n0;
    {
        const int cq = lane & 7, dg = lane >> 3;
        const bool cut = (n0 == 992) && (cq >= 2);
        #pragma unroll 4
        for (int it = 0; it < 32; ++it) {
            int d = it * 16 + dg * 2;
            float4 va = make_float4(0.f, 0.f, 0.f, 0.f), vb = va;
            if (!cut) {
                va = *(const float4*)(Wg + (size_t)d * 1000 + 4 * cq);
                vb = *(const float4*)(Wg + (size_t)(d + 1) * 1000 + 4 * cq);
            }
            *(unsigned*)&ws[(4 * cq + 0) * 520 + d] = pk2bf(va.x, vb.x);
            *(unsigned*)&ws[(4 * cq + 1) * 520 + d] = pk2bf(va.y, vb.y);
            *(unsigned*)&ws[(4 * cq + 2) * 520 + d] = pk2bf(va.z, vb.z);
            *(unsigned*)&ws[(4 * cq + 3) * 520 + d] = pk2bf(va.w, vb.w);
        }
    }
    __syncthreads();

    const int tok_a = tks[mn] < 0 ? 0 : tks[mn];
    const ushort_t* ha = h1b + (size_t)tok_a * 512;

    f32x16 acc;
    #pragma unroll
    for (int i = 0; i < 16; ++i) acc[i] = 0.f;

    #pragma unroll 4
    for (int kt = 0; kt < 16; ++kt) {
        int k0 = kt * 32;
        short8 a0 = *(const short8*)(ha + k0 + g * 8);
        short8 a1 = *(const short8*)(ha + k0 + 16 + g * 8);
        short8 b0 = *(const short8*)(&ws[mn * 520 + k0 + g * 8]);
        short8 b1 = *(const short8*)(&ws[mn * 520 + k0 + 16 + g * 8]);
        acc = MFMA32(a0, b0, acc);
        acc = MFMA32(a1, b1, acc);
    }

    const int col = n0 + mn;
    if (col < 1000) {
        const float bias = b2[e * 1000 + col];
        #pragma unroll
        for (int r = 0; r < 16; ++r) {
            int mrow = (r & 3) + 8 * (r >> 2) + 4 * g;
            int tok = tks[mrow];
            if (tok >= 0)
                out[(size_t)tok * 1000 + col] = acc[r] + bias;
        }
    }
}

extern "C" void kernel_launch(void* const* d_in, const int* in_sizes, int n_in,
                              void* d_out, int out_size, void* d_ws, size_t ws_size,
                              hipStream_t stream)
{
    const float* x   = (const float*)d_in[0];
    const float* c1w = (const float*)d_in[1];
    const float* c1b = (const float*)d_in[2];
    const float* c2w = (const float*)d_in[3];
    const float* c2b = (const float*)d_in[4];
    const float* c3w = (const float*)d_in[5];
    const float* c3b = (const float*)d_in[6];
    const float* c4w = (const float*)d_in[7];
    const float* c4b = (const float*)d_in[8];
    const float* pw  = (const float*)d_in[9];
    const float* pb  = (const float*)d_in[10];
    const float* rw  = (const float*)d_in[11];
    const float* rb  = (const float*)d_in[12];
    const float* w1  = (const float*)d_in[13];
    const float* b1  = (const float*)d_in[14];
    const float* w2  = (const float*)d_in[15];
    const float* b2  = (const float*)d_in[16];

    float* out = (float*)d_out;
    float* tail = out + 128000;   // aux, counts[16], importance[16]

    char* w = (char*)d_ws;
    ushort_t* a2   = (ushort_t*)(w);                  // 33554432 B
    ushort_t* a3   = (ushort_t*)(w + 33554432);       // 16777216 B
    ushort_t* w2f  = (ushort_t*)(w + 50331648);       // 18432 B
    ushort_t* w3f  = (ushort_t*)(w + 50350080);       // 36864 B
    ushort_t* w4f  = (ushort_t*)(w + 50386944);       // 73728 B
    ushort_t* c1f  = (ushort_t*)(w + 50460672);       // 3072 B
    float*    feat = (float*)(w + 50464768);          // 32768 B
    ushort_t* zb   = (ushort_t*)(w + 50497536);       // 131072 B
    ushort_t* h1b  = (ushort_t*)(w + 50628608);       // 131072 B
    int*      top1 = (int*)(w + 50759680);            // 512 B
    int*      meta = (int*)(w + 50760192);            // 512 B
    int*      perm = (int*)(w + 50760704);            // 512 B

    k_wcvt  <<<34, 256, 0, stream>>>(c1w, c1b, c2w, c3w, c4w, c1f, w2f, w3f, w4f, feat, tail);
    k_c12   <<<dim3(8, 8, 128), 512, 0, stream>>>(x, c1f, w2f, c2b, a2);
    k_c3    <<<dim3(4, 4, 128), 512, 0, stream>>>(a2, w3f, c3b, a3);
    k_c4    <<<dim3(2, 2, 128), 512, 0, stream>>>(a3, w4f, c4b, feat);
    k_router<<<128, 256, 0, stream>>>(feat, pw, pb, rw, rb, zb, top1, tail);
    k_sort  <<<1, 128, 0, stream>>>(top1, meta, perm, tail);
    k_mlp1  <<<dim3(16, 20), 64, 0, stream>>>(zb, meta, perm, w1, b1, h1b);
    k_mlp2  <<<dim3(32, 20), 64, 0, stream>>>(h1b, meta, perm, w2, b2, out);
}